// Round 6
// baseline (1800.283 us; speedup 1.0000x reference)
//
#include <hip/hip_runtime.h>
#include <math.h>

// ---------------- problem constants ----------------
constexpr int B_   = 16;
constexpr int D_   = 192;
constexpr int S_   = 48;
constexpr int NF_  = 8;
constexpr int C2_  = 97;   // D/2+1
constexpr int HID_ = 48;
constexpr int FS_  = 25;   // S/2+1
constexpr int HW_  = S_ * S_;    // 2304
constexpr int HWF_ = S_ * FS_;   // 1200
constexpr float EPS_ = 1e-5f;
constexpr double PI_D = 3.14159265358979323846;

// ---------------- prep: fold BN into conv_r/conv_t weights ----------------
__global__ __launch_bounds__(192) void k_prep(const float* __restrict__ crt_w,
                                              const float* __restrict__ crt_b,
                                              const float* __restrict__ bn_g,
                                              const float* __restrict__ bn_b,
                                              float* __restrict__ Weff,
                                              float* __restrict__ beff)
{
    int io = blockIdx.x;            // i*192 + o
    int c  = threadIdx.x;           // 0..191
    int i  = io / D_;
    float s  = bn_g[i * D_ + c] * rsqrtf(1.f + EPS_);
    float bb = bn_b[i * D_ + c];
    float w  = crt_w[(size_t)io * D_ + c];
    Weff[(size_t)io * D_ + c] = w * s;
    __shared__ float red[D_];
    red[c] = w * bb;
    __syncthreads();
    if (c == 0) {
        float acc = 0.f;
        for (int j = 0; j < D_; ++j) acc += red[j];
        int o = io % D_;
        beff[io] = crt_b[i * D_ + o] + acc;
    }
}

// ---------------- mean over HW of bn(r)+bn(t) ----------------
__global__ __launch_bounds__(256) void k_mean(const float* __restrict__ r,
                                              const float* __restrict__ t,
                                              const float* __restrict__ bn_g,
                                              const float* __restrict__ bn_b,
                                              float* __restrict__ xm)
{
    int bd = blockIdx.x;
    int d  = bd % D_;
    float sr = bn_g[d]      * rsqrtf(1.f + EPS_);
    float st = bn_g[D_ + d] * rsqrtf(1.f + EPS_);
    const float* rp = r + (size_t)bd * HW_;
    const float* tp = t + (size_t)bd * HW_;
    float acc = 0.f;
    for (int i = threadIdx.x; i < HW_; i += 256) acc += rp[i] * sr + tp[i] * st;
    __shared__ float red[256];
    red[threadIdx.x] = acc;
    __syncthreads();
    for (int off = 128; off > 0; off >>= 1) {
        if (threadIdx.x < off) red[threadIdx.x] += red[threadIdx.x + off];
        __syncthreads();
    }
    if (threadIdx.x == 0)
        xm[bd] = red[0] * (1.f / HW_) + bn_b[d] + bn_b[D_ + d];
}

// ---------------- routing MLP + softmax over filters ----------------
__global__ __launch_bounds__(192) void k_route(const float* __restrict__ xm,
                                               const float* __restrict__ fc1,
                                               const float* __restrict__ fc2,
                                               const float* __restrict__ star_s,
                                               const float* __restrict__ star_b,
                                               float* __restrict__ route)
{
    int b = blockIdx.x;
    int tid = threadIdx.x;          // 0..191
    __shared__ float x[D_];
    __shared__ float h[HID_];
    x[tid] = xm[b * D_ + tid];
    __syncthreads();
    if (tid < HID_) {
        float a = 0.f;
        const float* wp = fc1 + (size_t)tid * D_;
        for (int c = 0; c < D_; ++c) a += x[c] * wp[c];
        float rl = fmaxf(a, 0.f);
        h[tid] = star_s[2] * rl * rl + star_b[2];
    }
    __syncthreads();
    float lg[NF_];
    for (int f = 0; f < NF_; ++f) {
        const float* wp = fc2 + ((size_t)f * D_ + tid) * HID_;
        float a = 0.f;
        for (int j = 0; j < HID_; ++j) a += h[j] * wp[j];
        lg[f] = a;
    }
    float m = lg[0];
    for (int f = 1; f < NF_; ++f) m = fmaxf(m, lg[f]);
    float ssum = 0.f;
    for (int f = 0; f < NF_; ++f) { lg[f] = expf(lg[f] - m); ssum += lg[f]; }
    float inv = 1.f / ssum;
    for (int f = 0; f < NF_; ++f)
        route[((size_t)b * NF_ + f) * D_ + tid] = lg[f] * inv;
}

// ---------------- channel-GEMM (1x1 conv), 64(O)x128(N) tile, 4x8 acc ----------------
// out[b,o,hw] = act( sum_c W[o,c]*in[b,c,hw] + bias[o] )
// act: 0 none, 1 leaky(0.1), 2 StarReLU, 3 fused combine (atomicAdd sc*exp(i v) into rre/rim)
// z-batch: pointers advanced by z*stride (elements).
__global__ __launch_bounds__(256) void k_gemm(const float* __restrict__ in,
                                              const float* __restrict__ W,
                                              const float* __restrict__ bias,
                                              float* __restrict__ outp,
                                              int Cin, int Cout, int HWl, int NB, int act,
                                              const float* __restrict__ ssp,
                                              const float* __restrict__ sbp, int sidx,
                                              long instr, long wstr, long bstr, long ostr,
                                              const float* __restrict__ scp,
                                              float* __restrict__ rre,
                                              float* __restrict__ rim)
{
    const int z = blockIdx.z;
    in   += (long)z * instr;
    W    += (long)z * wstr;
    bias += (long)z * bstr;
    outp += (long)z * ostr;

    const int n0 = blockIdx.x * 128;
    const int o0 = blockIdx.y * 64;
    const int tid = threadIdx.x;
    const int tx = tid & 15;        // N group: cols tx*8..+8
    const int ty = tid >> 4;        // O group: rows ty*4..+4
    __shared__ float As[16][72];    // [k][o], 64+pad (row=288B, 16B aligned)
    __shared__ float Bs[16][136];   // [k][n], 128+pad (row=544B, 16B aligned)
    float acc[4][8] = {};
    const int Ntot = NB * HWl;

    // A loader coords: kk fixed per thread, 4 strided o values
    const int akk = tid & 15, aoo0 = tid >> 4;
    // B loader coords: nn fixed per thread, 8 kk values
    const int nn = tid & 127, kb = tid >> 7;      // kb in {0,1}
    const int n = n0 + nn;
    const bool nok = n < Ntot;
    int bidx = 0, hw = 0;
    if (nok) { bidx = n / HWl; hw = n % HWl; }
    const float* bp = in + (size_t)bidx * Cin * HWl + hw;

    for (int k0 = 0; k0 < Cin; k0 += 16) {
        #pragma unroll
        for (int j = 0; j < 4; ++j) {
            int oo = aoo0 + 16 * j;
            int o  = o0 + oo;
            int k  = k0 + akk;
            As[akk][oo] = (o < Cout && k < Cin) ? W[(size_t)o * Cin + k] : 0.f;
        }
        #pragma unroll
        for (int j = 0; j < 8; ++j) {
            int kk = kb * 8 + j;
            int k  = k0 + kk;
            Bs[kk][nn] = (nok && k < Cin) ? bp[(size_t)k * HWl] : 0.f;
        }
        __syncthreads();
        #pragma unroll
        for (int kk = 0; kk < 16; ++kk) {
            float4 av = *reinterpret_cast<const float4*>(&As[kk][ty * 4]);
            float4 b0 = *reinterpret_cast<const float4*>(&Bs[kk][tx * 8]);
            float4 b1 = *reinterpret_cast<const float4*>(&Bs[kk][tx * 8 + 4]);
            float a4[4] = {av.x, av.y, av.z, av.w};
            float b8[8] = {b0.x, b0.y, b0.z, b0.w, b1.x, b1.y, b1.z, b1.w};
            #pragma unroll
            for (int i = 0; i < 4; ++i)
                #pragma unroll
                for (int j = 0; j < 8; ++j)
                    acc[i][j] += a4[i] * b8[j];
        }
        __syncthreads();
    }

    float ss = 0.f, sb = 0.f;
    if (act == 2) { ss = ssp[sidx]; sb = sbp[sidx]; }
    #pragma unroll
    for (int i = 0; i < 4; ++i) {
        int o = o0 + ty * 4 + i;
        if (o >= Cout) continue;
        float bs = bias[o];
        #pragma unroll
        for (int j = 0; j < 8; ++j) {
            int nj = n0 + tx * 8 + j;
            if (nj >= Ntot) continue;
            float v = acc[i][j] + bs;
            int bb = nj / HWl, hh = nj % HWl;
            size_t oi = ((size_t)bb * Cout + o) * HWl + hh;
            if (act == 3) {
                float s = scp[oi];
                float sn, cs; sincosf(v, &sn, &cs);
                atomicAdd(&rre[oi], s * cs);
                atomicAdd(&rim[oi], s * sn);
            } else {
                if (act == 1)      v = v >= 0.f ? v : 0.1f * v;
                else if (act == 2) { float rl = fmaxf(v, 0.f); v = ss * rl * rl + sb; }
                outp[oi] = v;
            }
        }
    }
}

// ---------------- rfft2 (ortho) of one [48,48] map -> abs & angle [48,25] ----------------
__global__ __launch_bounds__(256) void k_rfft2(const float* __restrict__ u,
                                               float* __restrict__ A,
                                               float* __restrict__ P)
{
    int bd = blockIdx.x;
    __shared__ float tu[HW_];
    __shared__ float rre[HWF_], rim[HWF_];
    __shared__ float tc[S_], ts[S_];
    int t = threadIdx.x;
    if (t < S_) { double ang = -2.0 * PI_D * (double)t / (double)S_; tc[t] = (float)cos(ang); ts[t] = (float)sin(ang); }
    for (int i = t; i < HW_; i += 256) tu[i] = u[(size_t)bd * HW_ + i];
    __syncthreads();
    for (int i = t; i < HWF_; i += 256) {
        int h = i / FS_, k = i % FS_;
        float ar = 0.f, ai = 0.f;
        int m = 0;
        for (int w = 0; w < S_; ++w) {
            float v = tu[h * S_ + w];
            ar += v * tc[m]; ai += v * ts[m];
            m += k; if (m >= S_) m -= S_;
        }
        rre[i] = ar; rim[i] = ai;
    }
    __syncthreads();
    for (int i = t; i < HWF_; i += 256) {
        int kh = i / FS_, w = i % FS_;
        float ar = 0.f, ai = 0.f;
        int m = 0;
        for (int h = 0; h < S_; ++h) {
            float xr = rre[h * FS_ + w], xi = rim[h * FS_ + w];
            float c = tc[m], s = ts[m];
            ar += xr * c - xi * s;
            ai += xr * s + xi * c;
            m += kh; if (m >= S_) m -= S_;
        }
        ar *= (1.f / 48.f); ai *= (1.f / 48.f);
        A[(size_t)bd * HWF_ + i] = sqrtf(ar * ar + ai * ai);
        P[(size_t)bd * HWF_ + i] = atan2f(ai, ar);
    }
}

// ---------------- channel rfft (ortho) of amplitude a: 192 -> 97 ----------------
__global__ __launch_bounds__(256) void k_chfft(const float* __restrict__ A,
                                               float* __restrict__ CA,
                                               float* __restrict__ CP)
{
    int bh = blockIdx.x;
    int b = bh / S_, h = bh % S_;
    __shared__ float ta[D_ * FS_];
    __shared__ float tc[D_], ts[D_];
    int t = threadIdx.x;
    for (int i = t; i < D_; i += 256) {
        double ang = -2.0 * PI_D * (double)i / (double)D_;
        tc[i] = (float)cos(ang); ts[i] = (float)sin(ang);
    }
    for (int i = t; i < D_ * FS_; i += 256) {
        int d = i / FS_, w = i % FS_;
        ta[i] = A[(((size_t)b * D_ + d) * S_ + h) * FS_ + w];
    }
    __syncthreads();
    const float nrm = rsqrtf((float)D_);
    for (int i = t; i < C2_ * FS_; i += 256) {
        int k = i / FS_, w = i % FS_;
        float ar = 0.f, ai = 0.f;
        int m = 0;
        for (int d = 0; d < D_; ++d) {
            float v = ta[d * FS_ + w];
            ar += v * tc[m]; ai += v * ts[m];
            m += k; if (m >= D_) m -= D_;
        }
        ar *= nrm; ai *= nrm;
        size_t o = (((size_t)b * C2_ + k) * S_ + h) * FS_ + w;
        CA[o] = sqrtf(ar * ar + ai * ai);
        CP[o] = atan2f(ai, ar);
    }
}

// ---------------- channel irfft (ortho, 97->192); sc = c*a in place ----------------
__global__ __launch_bounds__(256) void k_chirfft(const float* __restrict__ CAe,
                                                 const float* __restrict__ CPe,
                                                 float* __restrict__ Asc)
{
    int bh = blockIdx.x;
    int b = bh / S_, h = bh % S_;
    __shared__ float Ar[C2_ * FS_], Ai[C2_ * FS_];
    __shared__ float tc[D_], ts[D_];
    int t = threadIdx.x;
    for (int i = t; i < D_; i += 256) {
        double ang = 2.0 * PI_D * (double)i / (double)D_;
        tc[i] = (float)cos(ang); ts[i] = (float)sin(ang);
    }
    for (int i = t; i < C2_ * FS_; i += 256) {
        int k = i / FS_, w = i % FS_;
        size_t o = (((size_t)b * C2_ + k) * S_ + h) * FS_ + w;
        float amp = CAe[o], ph = CPe[o];
        float sn, cs; sincosf(ph, &sn, &cs);
        Ar[i] = amp * cs; Ai[i] = amp * sn;
    }
    __syncthreads();
    const float nrm = rsqrtf((float)D_);
    for (int i = t; i < D_ * FS_; i += 256) {
        int d = i / FS_, w = i % FS_;
        float acc = Ar[w] + ((d & 1) ? -1.f : 1.f) * Ar[(C2_ - 1) * FS_ + w];
        float s2 = 0.f;
        int m = d;
        for (int k = 1; k < C2_ - 1; ++k) {
            s2 += Ar[k * FS_ + w] * tc[m] - Ai[k * FS_ + w] * ts[m];
            m += d; if (m >= D_) m -= D_;
        }
        float c = (acc + 2.f * s2) * nrm;
        size_t o = (((size_t)b * D_ + d) * S_ + h) * FS_ + w;
        Asc[o] = c * Asc[o];
    }
}

// ---------------- spectrum * routed filter, irfft2 (ortho), + residuals -> out_1 ----------------
__global__ __launch_bounds__(256) void k_final(const float* __restrict__ rre,
                                               const float* __restrict__ rim,
                                               const float* __restrict__ route,
                                               const float* __restrict__ cw,
                                               const float* __restrict__ rin,
                                               const float* __restrict__ tin,
                                               float* __restrict__ out1)
{
    int bd = blockIdx.x;
    int b = bd / D_, d = bd % D_;
    __shared__ float sRe[HWF_], sIm[HWF_];
    __shared__ float cRe[HWF_], cIm[HWF_];
    __shared__ float tc[S_], ts[S_];
    __shared__ float rt[NF_];
    int t = threadIdx.x;
    if (t < S_) { double ang = 2.0 * PI_D * (double)t / (double)S_; tc[t] = (float)cos(ang); ts[t] = (float)sin(ang); }
    if (t < NF_) rt[t] = route[((size_t)b * NF_ + t) * D_ + d];
    __syncthreads();
    for (int i = t; i < HWF_; i += 256) {
        const float* cwp = cw + (size_t)i * NF_ * 2;
        float wr = 0.f, wi = 0.f;
        #pragma unroll
        for (int f = 0; f < NF_; ++f) { wr += rt[f] * cwp[2 * f]; wi += rt[f] * cwp[2 * f + 1]; }
        float xr = rre[(size_t)bd * HWF_ + i], xi = rim[(size_t)bd * HWF_ + i];
        sRe[i] = xr * wr - xi * wi;
        sIm[i] = xr * wi + xi * wr;
    }
    __syncthreads();
    for (int i = t; i < HWF_; i += 256) {
        int hp = i / FS_, w = i % FS_;
        float ar = 0.f, ai = 0.f;
        int m = 0;
        for (int h = 0; h < S_; ++h) {
            float xr = sRe[h * FS_ + w], xi = sIm[h * FS_ + w];
            ar += xr * tc[m] - xi * ts[m];
            ai += xr * ts[m] + xi * tc[m];
            m += hp; if (m >= S_) m -= S_;
        }
        cRe[i] = ar; cIm[i] = ai;
    }
    __syncthreads();
    for (int i = t; i < HW_; i += 256) {
        int hp = i / S_, n = i % S_;
        float acc = cRe[hp * FS_] + ((n & 1) ? -1.f : 1.f) * cRe[hp * FS_ + FS_ - 1];
        float s2 = 0.f;
        int m = n;
        for (int k = 1; k < FS_ - 1; ++k) {
            s2 += cRe[hp * FS_ + k] * tc[m] - cIm[hp * FS_ + k] * ts[m];
            m += n; if (m >= S_) m -= S_;
        }
        float v = (acc + 2.f * s2) * (1.f / 48.f);
        size_t o = (size_t)bd * HW_ + i;
        out1[o] = v + rin[o] + tin[o];
    }
}

// ---------------- BN + depthwise 3x3 + residual -> out ----------------
__global__ __launch_bounds__(256) void k_dw(const float* __restrict__ out1,
                                            const float* __restrict__ g,
                                            const float* __restrict__ bbn,
                                            const float* __restrict__ wdw,
                                            float* __restrict__ outp)
{
    int bd = blockIdx.x;
    int d = bd % D_;
    __shared__ float tile[HW_];
    int t = threadIdx.x;
    for (int i = t; i < HW_; i += 256) tile[i] = out1[(size_t)bd * HW_ + i];
    float sc = g[d] * rsqrtf(1.f + EPS_);
    float bb = bbn[d];
    float w9[9];
    #pragma unroll
    for (int q = 0; q < 9; ++q) w9[q] = wdw[d * 9 + q];
    __syncthreads();
    for (int i = t; i < HW_; i += 256) {
        int y = i / S_, x = i % S_;
        float acc = 0.f;
        #pragma unroll
        for (int ki = 0; ki < 3; ++ki) {
            int yy = y + ki - 1;
            if (yy < 0 || yy >= S_) continue;
            #pragma unroll
            for (int kj = 0; kj < 3; ++kj) {
                int xx = x + kj - 1;
                if (xx < 0 || xx >= S_) continue;
                acc += w9[ki * 3 + kj] * (tile[yy * S_ + xx] * sc + bb);
            }
        }
        outp[(size_t)bd * HW_ + i] = acc + tile[i];
    }
}

// ---------------- launch ----------------
extern "C" void kernel_launch(void* const* d_in, const int* in_sizes, int n_in,
                              void* d_out, int out_size, void* d_ws, size_t ws_size,
                              hipStream_t stream)
{
    (void)in_sizes; (void)n_in; (void)out_size; (void)ws_size;
    const float* r      = (const float*)d_in[0];
    const float* t      = (const float*)d_in[1];
    const float* bn_g   = (const float*)d_in[2];
    const float* bn_b   = (const float*)d_in[3];
    const float* crt_w  = (const float*)d_in[4];
    const float* crt_b  = (const float*)d_in[5];
    const float* star_s = (const float*)d_in[6];
    const float* star_b = (const float*)d_in[7];
    const float* fc1_w  = (const float*)d_in[8];
    const float* fc2_w  = (const float*)d_in[9];
    const float* cw     = (const float*)d_in[10];
    const float* enh_w1 = (const float*)d_in[11];
    const float* enh_b1 = (const float*)d_in[12];
    const float* enh_w2 = (const float*)d_in[13];
    const float* enh_b2 = (const float*)d_in[14];
    const float* ph_w1  = (const float*)d_in[15];
    const float* ph_b1  = (const float*)d_in[16];
    const float* ph_w2  = (const float*)d_in[17];
    const float* ph_b2  = (const float*)d_in[18];
    const float* dwbn_g = (const float*)d_in[19];
    const float* dwbn_b = (const float*)d_in[20];
    const float* dw_w   = (const float*)d_in[21];
    float* out = (float*)d_out;

    const long NDHWF = (long)B_ * D_ * HWF_;     // 3,686,400
    const long SLOTC = (long)B_ * C2_ * HWF_;    // 1,862,400

    float* ws = (float*)d_ws;
    size_t off = 0;
    float* UACT = ws + off; off += (size_t)B_ * D_ * HW_;    // conv act / CH / HT / out_1
    float* A_   = ws + off; off += NDHWF;                    // amplitude a -> sc
    float* P_   = ws + off; off += NDHWF;                    // phase p
    float* RRE  = ws + off; off += NDHWF;                    // rt_s real (memset 0)
    float* RIM  = ws + off; off += NDHWF;                    // rt_s imag (adjacent!)
    float* CA2  = ws + off; off += 2 * SLOTC;                // [2 slots]: ca, cp
    float* XM   = ws + off; off += B_ * D_;
    float* ROUTE= ws + off; off += B_ * NF_ * D_;
    float* WEFF = ws + off; off += 2 * D_ * D_;
    float* BEFF = ws + off; off += 2 * D_;
    float* CH   = UACT;   // enh hidden (2 slots, 3.72M <= 7.08M) — UACT dead after rfft2
    float* HT   = UACT;   // phase hidden — CH dead after enh L2

    // zero rt_s accumulators (RRE,RIM adjacent)
    hipMemsetAsync(RRE, 0, (size_t)(2 * NDHWF) * sizeof(float), stream);

    k_prep<<<2 * D_, D_, 0, stream>>>(crt_w, crt_b, bn_g, bn_b, WEFF, BEFF);
    k_mean<<<B_ * D_, 256, 0, stream>>>(r, t, bn_g, bn_b, XM);
    k_route<<<B_, D_, 0, stream>>>(XM, fc1_w, fc2_w, star_s, star_b, ROUTE);

    for (int br = 0; br < 2; ++br) {
        const float* u_in = (br == 0) ? r : t;
        const int ia = (br == 0) ? 0 : 2;   // ca-net (cp-net = ia+1, adjacent for z-batch)

        // u = StarReLU(conv1x1(BN(u_in)))
        k_gemm<<<dim3(288, 3, 1), 256, 0, stream>>>(u_in, WEFF + (size_t)br * D_ * D_, BEFF + br * D_,
            UACT, D_, D_, HW_, B_, 2, star_s, star_b, br, 0, 0, 0, 0, nullptr, nullptr, nullptr);
        // spatial rfft2 -> amplitude/phase
        k_rfft2<<<B_ * D_, 256, 0, stream>>>(UACT, A_, P_);
        // channel rfft of amplitude -> ca (slot 0), cp (slot 1)
        k_chfft<<<B_ * S_, 256, 0, stream>>>(A_, CA2, CA2 + SLOTC);
        // enhance nets, z-batched over {ca-net, cp-net}
        k_gemm<<<dim3(150, 2, 2), 256, 0, stream>>>(CA2, enh_w1 + (size_t)ia * C2_ * C2_, enh_b1 + ia * C2_,
            CH, C2_, C2_, HWF_, B_, 1, nullptr, nullptr, 0,
            SLOTC, (long)C2_ * C2_, C2_, SLOTC, nullptr, nullptr, nullptr);
        k_gemm<<<dim3(150, 2, 2), 256, 0, stream>>>(CH, enh_w2 + (size_t)ia * C2_ * C2_, enh_b2 + ia * C2_,
            CA2, C2_, C2_, HWF_, B_, 0, nullptr, nullptr, 0,
            SLOTC, (long)C2_ * C2_, C2_, SLOTC, nullptr, nullptr, nullptr);
        // channel irfft of caE*exp(i cpE); sc = c*a in place over A_
        k_chirfft<<<B_ * S_, 256, 0, stream>>>(CA2, CA2 + SLOTC, A_);
        // phase net on p; L2 epilogue fuses combine: rt_s += sc*exp(i pE)
        k_gemm<<<dim3(150, 3, 1), 256, 0, stream>>>(P_, ph_w1 + (size_t)br * D_ * D_, ph_b1 + br * D_,
            HT, D_, D_, HWF_, B_, 1, nullptr, nullptr, 0, 0, 0, 0, 0, nullptr, nullptr, nullptr);
        k_gemm<<<dim3(150, 3, 1), 256, 0, stream>>>(HT, ph_w2 + (size_t)br * D_ * D_, ph_b2 + br * D_,
            P_, D_, D_, HWF_, B_, 3, nullptr, nullptr, 0, 0, 0, 0, 0, A_, RRE, RIM);
    }

    // spectrum * routed filters, irfft2, + residuals -> out_1 (in UACT)
    k_final<<<B_ * D_, 256, 0, stream>>>(RRE, RIM, ROUTE, cw, r, t, UACT);
    // BN + depthwise 3x3 + residual -> out
    k_dw<<<B_ * D_, 256, 0, stream>>>(UACT, dwbn_g, dwbn_b, dw_w, out);
}

// Round 12
// 1500.504 us; speedup vs baseline: 1.1998x; 1.1998x over previous
//
#include <hip/hip_runtime.h>
#include <math.h>

// ---------------- problem constants ----------------
constexpr int B_   = 16;
constexpr int D_   = 192;
constexpr int S_   = 48;
constexpr int NF_  = 8;
constexpr int C2_  = 97;   // D/2+1
constexpr int HID_ = 48;
constexpr int FS_  = 25;   // S/2+1
constexpr int HW_  = S_ * S_;    // 2304
constexpr int HWF_ = S_ * FS_;   // 1200
constexpr float EPS_ = 1e-5f;
constexpr double PI_D = 3.14159265358979323846;

// ---------------- prep: fold BN into conv_r/conv_t weights ----------------
__global__ __launch_bounds__(192) void k_prep(const float* __restrict__ crt_w,
                                              const float* __restrict__ crt_b,
                                              const float* __restrict__ bn_g,
                                              const float* __restrict__ bn_b,
                                              float* __restrict__ Weff,
                                              float* __restrict__ beff)
{
    int io = blockIdx.x;            // i*192 + o
    int c  = threadIdx.x;           // 0..191
    int i  = io / D_;
    float s  = bn_g[i * D_ + c] * rsqrtf(1.f + EPS_);
    float bb = bn_b[i * D_ + c];
    float w  = crt_w[(size_t)io * D_ + c];
    Weff[(size_t)io * D_ + c] = w * s;
    __shared__ float red[D_];
    red[c] = w * bb;
    __syncthreads();
    if (c == 0) {
        float acc = 0.f;
        for (int j = 0; j < D_; ++j) acc += red[j];
        int o = io % D_;
        beff[io] = crt_b[i * D_ + o] + acc;
    }
}

// ---------------- mean over HW of bn(r)+bn(t) ----------------
__global__ __launch_bounds__(256) void k_mean(const float* __restrict__ r,
                                              const float* __restrict__ t,
                                              const float* __restrict__ bn_g,
                                              const float* __restrict__ bn_b,
                                              float* __restrict__ xm)
{
    int bd = blockIdx.x;
    int d  = bd % D_;
    float sr = bn_g[d]      * rsqrtf(1.f + EPS_);
    float st = bn_g[D_ + d] * rsqrtf(1.f + EPS_);
    const float* rp = r + (size_t)bd * HW_;
    const float* tp = t + (size_t)bd * HW_;
    float acc = 0.f;
    for (int i = threadIdx.x; i < HW_; i += 256) acc += rp[i] * sr + tp[i] * st;
    __shared__ float red[256];
    red[threadIdx.x] = acc;
    __syncthreads();
    for (int off = 128; off > 0; off >>= 1) {
        if (threadIdx.x < off) red[threadIdx.x] += red[threadIdx.x + off];
        __syncthreads();
    }
    if (threadIdx.x == 0)
        xm[bd] = red[0] * (1.f / HW_) + bn_b[d] + bn_b[D_ + d];
}

// ---------------- routing MLP + softmax over filters ----------------
__global__ __launch_bounds__(192) void k_route(const float* __restrict__ xm,
                                               const float* __restrict__ fc1,
                                               const float* __restrict__ fc2,
                                               const float* __restrict__ star_s,
                                               const float* __restrict__ star_b,
                                               float* __restrict__ route)
{
    int b = blockIdx.x;
    int tid = threadIdx.x;          // 0..191
    __shared__ float x[D_];
    __shared__ float h[HID_];
    x[tid] = xm[b * D_ + tid];
    __syncthreads();
    if (tid < HID_) {
        float a = 0.f;
        const float* wp = fc1 + (size_t)tid * D_;
        for (int c = 0; c < D_; ++c) a += x[c] * wp[c];
        float rl = fmaxf(a, 0.f);
        h[tid] = star_s[2] * rl * rl + star_b[2];
    }
    __syncthreads();
    float lg[NF_];
    for (int f = 0; f < NF_; ++f) {
        const float* wp = fc2 + ((size_t)f * D_ + tid) * HID_;
        float a = 0.f;
        for (int j = 0; j < HID_; ++j) a += h[j] * wp[j];
        lg[f] = a;
    }
    float m = lg[0];
    for (int f = 1; f < NF_; ++f) m = fmaxf(m, lg[f]);
    float ssum = 0.f;
    for (int f = 0; f < NF_; ++f) { lg[f] = expf(lg[f] - m); ssum += lg[f]; }
    float inv = 1.f / ssum;
    for (int f = 0; f < NF_; ++f)
        route[((size_t)b * NF_ + f) * D_ + tid] = lg[f] * inv;
}

// ---------------- channel-GEMM (1x1 conv), 64(O)x128(N) tile, 4x8 acc ----------------
// out[b,o,hw] = act( sum_c W[o,c]*in[b,c,hw] + bias[o] )
// act: 0 none, 1 leaky(0.1), 2 StarReLU, 3 fused combine:
//   rre/rim {=, +=} sc*exp(i v)   (addf selects; NO atomics — each oi owned by one thread)
// z-batch: pointers advanced by z*stride (elements).
__global__ __launch_bounds__(256) void k_gemm(const float* __restrict__ in,
                                              const float* __restrict__ W,
                                              const float* __restrict__ bias,
                                              float* __restrict__ outp,
                                              int Cin, int Cout, int HWl, int NB, int act,
                                              const float* __restrict__ ssp,
                                              const float* __restrict__ sbp, int sidx,
                                              long instr, long wstr, long bstr, long ostr,
                                              const float* __restrict__ scp,
                                              float* __restrict__ rre,
                                              float* __restrict__ rim, int addf)
{
    const int z = blockIdx.z;
    in   += (long)z * instr;
    W    += (long)z * wstr;
    bias += (long)z * bstr;
    outp += (long)z * ostr;

    const int n0 = blockIdx.x * 128;
    const int o0 = blockIdx.y * 64;
    const int tid = threadIdx.x;
    const int tx = tid & 15;        // N group: cols tx*8..+8
    const int ty = tid >> 4;        // O group: rows ty*4..+4
    __shared__ float As[16][72];    // [k][o], 64+pad
    __shared__ float Bs[16][136];   // [k][n], 128+pad
    float acc[4][8] = {};
    const int Ntot = NB * HWl;

    const int akk = tid & 15, aoo0 = tid >> 4;
    const int nn = tid & 127, kb = tid >> 7;      // kb in {0,1}
    const int n = n0 + nn;
    const bool nok = n < Ntot;
    int bidx = 0, hw = 0;
    if (nok) { bidx = n / HWl; hw = n % HWl; }
    const float* bp = in + (size_t)bidx * Cin * HWl + hw;

    for (int k0 = 0; k0 < Cin; k0 += 16) {
        #pragma unroll
        for (int j = 0; j < 4; ++j) {
            int oo = aoo0 + 16 * j;
            int o  = o0 + oo;
            int k  = k0 + akk;
            As[akk][oo] = (o < Cout && k < Cin) ? W[(size_t)o * Cin + k] : 0.f;
        }
        #pragma unroll
        for (int j = 0; j < 8; ++j) {
            int kk = kb * 8 + j;
            int k  = k0 + kk;
            Bs[kk][nn] = (nok && k < Cin) ? bp[(size_t)k * HWl] : 0.f;
        }
        __syncthreads();
        #pragma unroll
        for (int kk = 0; kk < 16; ++kk) {
            float4 av = *reinterpret_cast<const float4*>(&As[kk][ty * 4]);
            float4 b0 = *reinterpret_cast<const float4*>(&Bs[kk][tx * 8]);
            float4 b1 = *reinterpret_cast<const float4*>(&Bs[kk][tx * 8 + 4]);
            float a4[4] = {av.x, av.y, av.z, av.w};
            float b8[8] = {b0.x, b0.y, b0.z, b0.w, b1.x, b1.y, b1.z, b1.w};
            #pragma unroll
            for (int i = 0; i < 4; ++i)
                #pragma unroll
                for (int j = 0; j < 8; ++j)
                    acc[i][j] += a4[i] * b8[j];
        }
        __syncthreads();
    }

    float ss = 0.f, sb = 0.f;
    if (act == 2) { ss = ssp[sidx]; sb = sbp[sidx]; }
    #pragma unroll
    for (int i = 0; i < 4; ++i) {
        int o = o0 + ty * 4 + i;
        if (o >= Cout) continue;
        float bs = bias[o];
        #pragma unroll
        for (int j = 0; j < 8; ++j) {
            int nj = n0 + tx * 8 + j;
            if (nj >= Ntot) continue;
            float v = acc[i][j] + bs;
            int bb = nj / HWl, hh = nj % HWl;
            size_t oi = ((size_t)bb * Cout + o) * HWl + hh;
            if (act == 3) {
                float s = scp[oi];
                float sn, cs; sincosf(v, &sn, &cs);
                float re = s * cs, im = s * sn;
                if (addf) { rre[oi] += re; rim[oi] += im; }
                else      { rre[oi]  = re; rim[oi]  = im; }
            } else {
                if (act == 1)      v = v >= 0.f ? v : 0.1f * v;
                else if (act == 2) { float rl = fmaxf(v, 0.f); v = ss * rl * rl + sb; }
                outp[oi] = v;
            }
        }
    }
}

// ---------------- rfft2 (ortho) of one [48,48] map -> abs & angle [48,25] ----------------
__global__ __launch_bounds__(256) void k_rfft2(const float* __restrict__ u,
                                               float* __restrict__ A,
                                               float* __restrict__ P)
{
    int bd = blockIdx.x;
    __shared__ float tu[HW_];
    __shared__ float rre[HWF_], rim[HWF_];
    __shared__ float tc[S_], ts[S_];
    int t = threadIdx.x;
    if (t < S_) { double ang = -2.0 * PI_D * (double)t / (double)S_; tc[t] = (float)cos(ang); ts[t] = (float)sin(ang); }
    for (int i = t; i < HW_; i += 256) tu[i] = u[(size_t)bd * HW_ + i];
    __syncthreads();
    for (int i = t; i < HWF_; i += 256) {
        int h = i / FS_, k = i % FS_;
        float ar = 0.f, ai = 0.f;
        int m = 0;
        for (int w = 0; w < S_; ++w) {
            float v = tu[h * S_ + w];
            ar += v * tc[m]; ai += v * ts[m];
            m += k; if (m >= S_) m -= S_;
        }
        rre[i] = ar; rim[i] = ai;
    }
    __syncthreads();
    for (int i = t; i < HWF_; i += 256) {
        int kh = i / FS_, w = i % FS_;
        float ar = 0.f, ai = 0.f;
        int m = 0;
        for (int h = 0; h < S_; ++h) {
            float xr = rre[h * FS_ + w], xi = rim[h * FS_ + w];
            float c = tc[m], s = ts[m];
            ar += xr * c - xi * s;
            ai += xr * s + xi * c;
            m += kh; if (m >= S_) m -= S_;
        }
        ar *= (1.f / 48.f); ai *= (1.f / 48.f);
        A[(size_t)bd * HWF_ + i] = sqrtf(ar * ar + ai * ai);
        P[(size_t)bd * HWF_ + i] = atan2f(ai, ar);
    }
}

// ---------------- channel rfft (ortho) of amplitude a: 192 -> 97 ----------------
__global__ __launch_bounds__(256) void k_chfft(const float* __restrict__ A,
                                               float* __restrict__ CA,
                                               float* __restrict__ CP)
{
    int bh = blockIdx.x;
    int b = bh / S_, h = bh % S_;
    __shared__ float ta[D_ * FS_];
    __shared__ float tc[D_], ts[D_];
    int t = threadIdx.x;
    for (int i = t; i < D_; i += 256) {
        double ang = -2.0 * PI_D * (double)i / (double)D_;
        tc[i] = (float)cos(ang); ts[i] = (float)sin(ang);
    }
    for (int i = t; i < D_ * FS_; i += 256) {
        int d = i / FS_, w = i % FS_;
        ta[i] = A[(((size_t)b * D_ + d) * S_ + h) * FS_ + w];
    }
    __syncthreads();
    const float nrm = rsqrtf((float)D_);
    for (int i = t; i < C2_ * FS_; i += 256) {
        int k = i / FS_, w = i % FS_;
        float ar = 0.f, ai = 0.f;
        int m = 0;
        for (int d = 0; d < D_; ++d) {
            float v = ta[d * FS_ + w];
            ar += v * tc[m]; ai += v * ts[m];
            m += k; if (m >= D_) m -= D_;
        }
        ar *= nrm; ai *= nrm;
        size_t o = (((size_t)b * C2_ + k) * S_ + h) * FS_ + w;
        CA[o] = sqrtf(ar * ar + ai * ai);
        CP[o] = atan2f(ai, ar);
    }
}

// ---------------- channel irfft (ortho, 97->192); sc = c*a in place ----------------
__global__ __launch_bounds__(256) void k_chirfft(const float* __restrict__ CAe,
                                                 const float* __restrict__ CPe,
                                                 float* __restrict__ Asc)
{
    int bh = blockIdx.x;
    int b = bh / S_, h = bh % S_;
    __shared__ float Ar[C2_ * FS_], Ai[C2_ * FS_];
    __shared__ float tc[D_], ts[D_];
    int t = threadIdx.x;
    for (int i = t; i < D_; i += 256) {
        double ang = 2.0 * PI_D * (double)i / (double)D_;
        tc[i] = (float)cos(ang); ts[i] = (float)sin(ang);
    }
    for (int i = t; i < C2_ * FS_; i += 256) {
        int k = i / FS_, w = i % FS_;
        size_t o = (((size_t)b * C2_ + k) * S_ + h) * FS_ + w;
        float amp = CAe[o], ph = CPe[o];
        float sn, cs; sincosf(ph, &sn, &cs);
        Ar[i] = amp * cs; Ai[i] = amp * sn;
    }
    __syncthreads();
    const float nrm = rsqrtf((float)D_);
    for (int i = t; i < D_ * FS_; i += 256) {
        int d = i / FS_, w = i % FS_;
        float acc = Ar[w] + ((d & 1) ? -1.f : 1.f) * Ar[(C2_ - 1) * FS_ + w];
        float s2 = 0.f;
        int m = d;
        for (int k = 1; k < C2_ - 1; ++k) {
            s2 += Ar[k * FS_ + w] * tc[m] - Ai[k * FS_ + w] * ts[m];
            m += d; if (m >= D_) m -= D_;
        }
        float c = (acc + 2.f * s2) * nrm;
        size_t o = (((size_t)b * D_ + d) * S_ + h) * FS_ + w;
        Asc[o] = c * Asc[o];
    }
}

// ---------------- spectrum * routed filter, irfft2 (ortho), + residuals -> out_1 ----------------
__global__ __launch_bounds__(256) void k_final(const float* __restrict__ rre,
                                               const float* __restrict__ rim,
                                               const float* __restrict__ route,
                                               const float* __restrict__ cw,
                                               const float* __restrict__ rin,
                                               const float* __restrict__ tin,
                                               float* __restrict__ out1)
{
    int bd = blockIdx.x;
    int b = bd / D_, d = bd % D_;
    __shared__ float sRe[HWF_], sIm[HWF_];
    __shared__ float cRe[HWF_], cIm[HWF_];
    __shared__ float tc[S_], ts[S_];
    __shared__ float rt[NF_];
    int t = threadIdx.x;
    if (t < S_) { double ang = 2.0 * PI_D * (double)t / (double)S_; tc[t] = (float)cos(ang); ts[t] = (float)sin(ang); }
    if (t < NF_) rt[t] = route[((size_t)b * NF_ + t) * D_ + d];
    __syncthreads();
    for (int i = t; i < HWF_; i += 256) {
        const float* cwp = cw + (size_t)i * NF_ * 2;
        float wr = 0.f, wi = 0.f;
        #pragma unroll
        for (int f = 0; f < NF_; ++f) { wr += rt[f] * cwp[2 * f]; wi += rt[f] * cwp[2 * f + 1]; }
        float xr = rre[(size_t)bd * HWF_ + i], xi = rim[(size_t)bd * HWF_ + i];
        sRe[i] = xr * wr - xi * wi;
        sIm[i] = xr * wi + xi * wr;
    }
    __syncthreads();
    for (int i = t; i < HWF_; i += 256) {
        int hp = i / FS_, w = i % FS_;
        float ar = 0.f, ai = 0.f;
        int m = 0;
        for (int h = 0; h < S_; ++h) {
            float xr = sRe[h * FS_ + w], xi = sIm[h * FS_ + w];
            ar += xr * tc[m] - xi * ts[m];
            ai += xr * ts[m] + xi * tc[m];
            m += hp; if (m >= S_) m -= S_;
        }
        cRe[i] = ar; cIm[i] = ai;
    }
    __syncthreads();
    for (int i = t; i < HW_; i += 256) {
        int hp = i / S_, n = i % S_;
        float acc = cRe[hp * FS_] + ((n & 1) ? -1.f : 1.f) * cRe[hp * FS_ + FS_ - 1];
        float s2 = 0.f;
        int m = n;
        for (int k = 1; k < FS_ - 1; ++k) {
            s2 += cRe[hp * FS_ + k] * tc[m] - cIm[hp * FS_ + k] * ts[m];
            m += n; if (m >= S_) m -= S_;
        }
        float v = (acc + 2.f * s2) * (1.f / 48.f);
        size_t o = (size_t)bd * HW_ + i;
        out1[o] = v + rin[o] + tin[o];
    }
}

// ---------------- BN + depthwise 3x3 + residual -> out ----------------
__global__ __launch_bounds__(256) void k_dw(const float* __restrict__ out1,
                                            const float* __restrict__ g,
                                            const float* __restrict__ bbn,
                                            const float* __restrict__ wdw,
                                            float* __restrict__ outp)
{
    int bd = blockIdx.x;
    int d = bd % D_;
    __shared__ float tile[HW_];
    int t = threadIdx.x;
    for (int i = t; i < HW_; i += 256) tile[i] = out1[(size_t)bd * HW_ + i];
    float sc = g[d] * rsqrtf(1.f + EPS_);
    float bb = bbn[d];
    float w9[9];
    #pragma unroll
    for (int q = 0; q < 9; ++q) w9[q] = wdw[d * 9 + q];
    __syncthreads();
    for (int i = t; i < HW_; i += 256) {
        int y = i / S_, x = i % S_;
        float acc = 0.f;
        #pragma unroll
        for (int ki = 0; ki < 3; ++ki) {
            int yy = y + ki - 1;
            if (yy < 0 || yy >= S_) continue;
            #pragma unroll
            for (int kj = 0; kj < 3; ++kj) {
                int xx = x + kj - 1;
                if (xx < 0 || xx >= S_) continue;
                acc += w9[ki * 3 + kj] * (tile[yy * S_ + xx] * sc + bb);
            }
        }
        outp[(size_t)bd * HW_ + i] = acc + tile[i];
    }
}

// ---------------- launch ----------------
extern "C" void kernel_launch(void* const* d_in, const int* in_sizes, int n_in,
                              void* d_out, int out_size, void* d_ws, size_t ws_size,
                              hipStream_t stream)
{
    (void)in_sizes; (void)n_in; (void)out_size; (void)ws_size;
    const float* r      = (const float*)d_in[0];
    const float* t      = (const float*)d_in[1];
    const float* bn_g   = (const float*)d_in[2];
    const float* bn_b   = (const float*)d_in[3];
    const float* crt_w  = (const float*)d_in[4];
    const float* crt_b  = (const float*)d_in[5];
    const float* star_s = (const float*)d_in[6];
    const float* star_b = (const float*)d_in[7];
    const float* fc1_w  = (const float*)d_in[8];
    const float* fc2_w  = (const float*)d_in[9];
    const float* cw     = (const float*)d_in[10];
    const float* enh_w1 = (const float*)d_in[11];
    const float* enh_b1 = (const float*)d_in[12];
    const float* enh_w2 = (const float*)d_in[13];
    const float* enh_b2 = (const float*)d_in[14];
    const float* ph_w1  = (const float*)d_in[15];
    const float* ph_b1  = (const float*)d_in[16];
    const float* ph_w2  = (const float*)d_in[17];
    const float* ph_b2  = (const float*)d_in[18];
    const float* dwbn_g = (const float*)d_in[19];
    const float* dwbn_b = (const float*)d_in[20];
    const float* dw_w   = (const float*)d_in[21];
    float* out = (float*)d_out;

    const long NDHWF = (long)B_ * D_ * HWF_;     // 3,686,400
    const long SLOTC = (long)B_ * C2_ * HWF_;    // 1,862,400

    float* ws = (float*)d_ws;
    size_t off = 0;
    float* UACT = ws + off; off += (size_t)B_ * D_ * HW_;    // conv act / CH / HT / out_1
    float* A_   = ws + off; off += NDHWF;                    // amplitude a -> sc
    float* P_   = ws + off; off += NDHWF;                    // phase p
    float* RRE  = ws + off; off += NDHWF;                    // rt_s real
    float* RIM  = ws + off; off += NDHWF;                    // rt_s imag
    float* CA2  = ws + off; off += 2 * SLOTC;                // [2 slots]: ca, cp
    float* XM   = ws + off; off += B_ * D_;
    float* ROUTE= ws + off; off += B_ * NF_ * D_;
    float* WEFF = ws + off; off += 2 * D_ * D_;
    float* BEFF = ws + off; off += 2 * D_;
    float* CH   = UACT;   // enh hidden (2 slots) — UACT dead after rfft2
    float* HT   = UACT;   // phase hidden — CH dead after enh L2

    k_prep<<<2 * D_, D_, 0, stream>>>(crt_w, crt_b, bn_g, bn_b, WEFF, BEFF);
    k_mean<<<B_ * D_, 256, 0, stream>>>(r, t, bn_g, bn_b, XM);
    k_route<<<B_, 192, 0, stream>>>(XM, fc1_w, fc2_w, star_s, star_b, ROUTE);

    for (int br = 0; br < 2; ++br) {
        const float* u_in = (br == 0) ? r : t;
        const int ia = (br == 0) ? 0 : 2;   // ca-net (cp-net = ia+1, adjacent for z-batch)

        // u = StarReLU(conv1x1(BN(u_in)))
        k_gemm<<<dim3(288, 3, 1), 256, 0, stream>>>(u_in, WEFF + (size_t)br * D_ * D_, BEFF + br * D_,
            UACT, D_, D_, HW_, B_, 2, star_s, star_b, br, 0, 0, 0, 0, nullptr, nullptr, nullptr, 0);
        // spatial rfft2 -> amplitude/phase
        k_rfft2<<<B_ * D_, 256, 0, stream>>>(UACT, A_, P_);
        // channel rfft of amplitude -> ca (slot 0), cp (slot 1)
        k_chfft<<<B_ * S_, 256, 0, stream>>>(A_, CA2, CA2 + SLOTC);
        // enhance nets, z-batched over {ca-net, cp-net}
        k_gemm<<<dim3(150, 2, 2), 256, 0, stream>>>(CA2, enh_w1 + (size_t)ia * C2_ * C2_, enh_b1 + ia * C2_,
            CH, C2_, C2_, HWF_, B_, 1, nullptr, nullptr, 0,
            SLOTC, (long)C2_ * C2_, C2_, SLOTC, nullptr, nullptr, nullptr, 0);
        k_gemm<<<dim3(150, 2, 2), 256, 0, stream>>>(CH, enh_w2 + (size_t)ia * C2_ * C2_, enh_b2 + ia * C2_,
            CA2, C2_, C2_, HWF_, B_, 0, nullptr, nullptr, 0,
            SLOTC, (long)C2_ * C2_, C2_, SLOTC, nullptr, nullptr, nullptr, 0);
        // channel irfft of caE*exp(i cpE); sc = c*a in place over A_
        k_chirfft<<<B_ * S_, 256, 0, stream>>>(CA2, CA2 + SLOTC, A_);
        // phase net on p; L2 epilogue fuses combine: rt_s {=,+=} sc*exp(i pE)  (no atomics)
        k_gemm<<<dim3(150, 3, 1), 256, 0, stream>>>(P_, ph_w1 + (size_t)br * D_ * D_, ph_b1 + br * D_,
            HT, D_, D_, HWF_, B_, 1, nullptr, nullptr, 0, 0, 0, 0, 0, nullptr, nullptr, nullptr, 0);
        k_gemm<<<dim3(150, 3, 1), 256, 0, stream>>>(HT, ph_w2 + (size_t)br * D_ * D_, ph_b2 + br * D_,
            P_, D_, D_, HWF_, B_, 3, nullptr, nullptr, 0, 0, 0, 0, 0, A_, RRE, RIM, br);
    }

    // spectrum * routed filters, irfft2, + residuals -> out_1 (in UACT)
    k_final<<<B_ * D_, 256, 0, stream>>>(RRE, RIM, ROUTE, cw, r, t, UACT);
    // BN + depthwise 3x3 + residual -> out
    k_dw<<<B_ * D_, 256, 0, stream>>>(UACT, dwbn_g, dwbn_b, dw_w, out);
}

// Round 13
// 1442.770 us; speedup vs baseline: 1.2478x; 1.0400x over previous
//
#include <hip/hip_runtime.h>
#include <math.h>

// ---------------- problem constants ----------------
constexpr int B_   = 16;
constexpr int D_   = 192;
constexpr int S_   = 48;
constexpr int NF_  = 8;
constexpr int C2_  = 97;   // D/2+1
constexpr int HID_ = 48;
constexpr int FS_  = 25;   // S/2+1
constexpr int HW_  = S_ * S_;    // 2304
constexpr int HWF_ = S_ * FS_;   // 1200
constexpr int CIN2_ = 2 * C2_;   // 194 (stacked Re;Im)
constexpr float EPS_ = 1e-5f;
constexpr double PI_D = 3.14159265358979323846;

// ---------------- prep: fold BN into conv_r/conv_t weights ----------------
__global__ __launch_bounds__(192) void k_prep(const float* __restrict__ crt_w,
                                              const float* __restrict__ crt_b,
                                              const float* __restrict__ bn_g,
                                              const float* __restrict__ bn_b,
                                              float* __restrict__ Weff,
                                              float* __restrict__ beff)
{
    int io = blockIdx.x;            // i*192 + o
    int c  = threadIdx.x;           // 0..191
    int i  = io / D_;
    float s  = bn_g[i * D_ + c] * rsqrtf(1.f + EPS_);
    float bb = bn_b[i * D_ + c];
    float w  = crt_w[(size_t)io * D_ + c];
    Weff[(size_t)io * D_ + c] = w * s;
    __shared__ float red[D_];
    red[c] = w * bb;
    __syncthreads();
    if (c == 0) {
        float acc = 0.f;
        for (int j = 0; j < D_; ++j) acc += red[j];
        int o = io % D_;
        beff[io] = crt_b[i * D_ + o] + acc;
    }
}

// ---------------- forward channel-DFT twiddles: Wfc,Wfs [97][192] ----------------
__global__ __launch_bounds__(192) void k_twidf(float* __restrict__ TWF)
{
    int k = blockIdx.x;     // 0..96
    int d = threadIdx.x;    // 0..191
    double ang = 2.0 * PI_D * (double)(k * d) / (double)D_;
    float nrm = rsqrtf((float)D_);
    TWF[k * D_ + d]              = (float)cos(ang) * nrm;     // Re part of e^{-i ang}
    TWF[C2_ * D_ + k * D_ + d]   = (float)(-sin(ang)) * nrm;  // Im part
}

// ---------------- inverse channel-DFT twiddles: Vinv [192][194] ----------------
// c[d] = sum_k Vinv[d][k]*Re_k + sum_j Vinv[d][97+j]*Im_j  (ortho irfft, n=192)
__global__ __launch_bounds__(256) void k_twidi(float* __restrict__ TWI)
{
    int d = blockIdx.x;     // 0..191
    int k = threadIdx.x;    // 0..255
    if (k >= CIN2_) return;
    float nrm = rsqrtf((float)D_);
    int j = (k < C2_) ? k : k - C2_;
    double ang = 2.0 * PI_D * (double)(j * d) / (double)D_;
    float v;
    if (k < C2_) {
        if (j == 0)       v = nrm;
        else if (j == 96) v = (d & 1) ? -nrm : nrm;
        else              v = 2.f * (float)cos(ang) * nrm;
    } else {
        if (j == 0 || j == 96) v = 0.f;
        else                   v = -2.f * (float)sin(ang) * nrm;
    }
    TWI[d * CIN2_ + k] = v;
}

// ---------------- mean over HW of bn(r)+bn(t) ----------------
__global__ __launch_bounds__(256) void k_mean(const float* __restrict__ r,
                                              const float* __restrict__ t,
                                              const float* __restrict__ bn_g,
                                              const float* __restrict__ bn_b,
                                              float* __restrict__ xm)
{
    int bd = blockIdx.x;
    int d  = bd % D_;
    float sr = bn_g[d]      * rsqrtf(1.f + EPS_);
    float st = bn_g[D_ + d] * rsqrtf(1.f + EPS_);
    const float* rp = r + (size_t)bd * HW_;
    const float* tp = t + (size_t)bd * HW_;
    float acc = 0.f;
    for (int i = threadIdx.x; i < HW_; i += 256) acc += rp[i] * sr + tp[i] * st;
    __shared__ float red[256];
    red[threadIdx.x] = acc;
    __syncthreads();
    for (int off = 128; off > 0; off >>= 1) {
        if (threadIdx.x < off) red[threadIdx.x] += red[threadIdx.x + off];
        __syncthreads();
    }
    if (threadIdx.x == 0)
        xm[bd] = red[0] * (1.f / HW_) + bn_b[d] + bn_b[D_ + d];
}

// ---------------- routing MLP + softmax over filters ----------------
__global__ __launch_bounds__(192) void k_route(const float* __restrict__ xm,
                                               const float* __restrict__ fc1,
                                               const float* __restrict__ fc2,
                                               const float* __restrict__ star_s,
                                               const float* __restrict__ star_b,
                                               float* __restrict__ route)
{
    int b = blockIdx.x;
    int tid = threadIdx.x;          // 0..191
    __shared__ float x[D_];
    __shared__ float h[HID_];
    x[tid] = xm[b * D_ + tid];
    __syncthreads();
    if (tid < HID_) {
        float a = 0.f;
        const float* wp = fc1 + (size_t)tid * D_;
        for (int c = 0; c < D_; ++c) a += x[c] * wp[c];
        float rl = fmaxf(a, 0.f);
        h[tid] = star_s[2] * rl * rl + star_b[2];
    }
    __syncthreads();
    float lg[NF_];
    for (int f = 0; f < NF_; ++f) {
        const float* wp = fc2 + ((size_t)f * D_ + tid) * HID_;
        float a = 0.f;
        for (int j = 0; j < HID_; ++j) a += h[j] * wp[j];
        lg[f] = a;
    }
    float m = lg[0];
    for (int f = 1; f < NF_; ++f) m = fmaxf(m, lg[f]);
    float ssum = 0.f;
    for (int f = 0; f < NF_; ++f) { lg[f] = expf(lg[f] - m); ssum += lg[f]; }
    float inv = 1.f / ssum;
    for (int f = 0; f < NF_; ++f)
        route[((size_t)b * NF_ + f) * D_ + tid] = lg[f] * inv;
}

// ---------------- channel-GEMM (1x1 conv), 64(O)x128(N) tile, 4x8 acc ----------------
// out[b,o,hw] = act( sum_c W[o,c]*in[b,c,hw] + bias[o] )   bias may be nullptr (=0)
// act: 0 none, 1 leaky(0.1), 2 StarReLU,
//      3 fused combine: rre/rim {=,+=} scp[oi]*exp(i v)  (addf; no atomics, oi owner-unique)
//      4 scale: out = v * scp[oi]
// z-batch: pointers advanced by z*stride (elements).
__global__ __launch_bounds__(256) void k_gemm(const float* __restrict__ in,
                                              const float* __restrict__ W,
                                              const float* __restrict__ bias,
                                              float* __restrict__ outp,
                                              int Cin, int Cout, int HWl, int NB, int act,
                                              const float* __restrict__ ssp,
                                              const float* __restrict__ sbp, int sidx,
                                              long instr, long wstr, long bstr, long ostr,
                                              const float* __restrict__ scp,
                                              float* __restrict__ rre,
                                              float* __restrict__ rim, int addf)
{
    const int z = blockIdx.z;
    in   += (long)z * instr;
    W    += (long)z * wstr;
    if (bias) bias += (long)z * bstr;
    outp += (long)z * ostr;

    const int n0 = blockIdx.x * 128;
    const int o0 = blockIdx.y * 64;
    const int tid = threadIdx.x;
    const int tx = tid & 15;        // N group: cols tx*8..+8
    const int ty = tid >> 4;        // O group: rows ty*4..+4
    __shared__ float As[16][72];    // [k][o], 64+pad
    __shared__ float Bs[16][136];   // [k][n], 128+pad
    float acc[4][8] = {};
    const int Ntot = NB * HWl;

    const int akk = tid & 15, aoo0 = tid >> 4;
    const int nn = tid & 127, kb = tid >> 7;      // kb in {0,1}
    const int n = n0 + nn;
    const bool nok = n < Ntot;
    int bidx = 0, hw = 0;
    if (nok) { bidx = n / HWl; hw = n % HWl; }
    const float* bp = in + (size_t)bidx * Cin * HWl + hw;

    for (int k0 = 0; k0 < Cin; k0 += 16) {
        #pragma unroll
        for (int j = 0; j < 4; ++j) {
            int oo = aoo0 + 16 * j;
            int o  = o0 + oo;
            int k  = k0 + akk;
            As[akk][oo] = (o < Cout && k < Cin) ? W[(size_t)o * Cin + k] : 0.f;
        }
        #pragma unroll
        for (int j = 0; j < 8; ++j) {
            int kk = kb * 8 + j;
            int k  = k0 + kk;
            Bs[kk][nn] = (nok && k < Cin) ? bp[(size_t)k * HWl] : 0.f;
        }
        __syncthreads();
        #pragma unroll
        for (int kk = 0; kk < 16; ++kk) {
            float4 av = *reinterpret_cast<const float4*>(&As[kk][ty * 4]);
            float4 b0 = *reinterpret_cast<const float4*>(&Bs[kk][tx * 8]);
            float4 b1 = *reinterpret_cast<const float4*>(&Bs[kk][tx * 8 + 4]);
            float a4[4] = {av.x, av.y, av.z, av.w};
            float b8[8] = {b0.x, b0.y, b0.z, b0.w, b1.x, b1.y, b1.z, b1.w};
            #pragma unroll
            for (int i = 0; i < 4; ++i)
                #pragma unroll
                for (int j = 0; j < 8; ++j)
                    acc[i][j] += a4[i] * b8[j];
        }
        __syncthreads();
    }

    float ss = 0.f, sb = 0.f;
    if (act == 2) { ss = ssp[sidx]; sb = sbp[sidx]; }
    #pragma unroll
    for (int i = 0; i < 4; ++i) {
        int o = o0 + ty * 4 + i;
        if (o >= Cout) continue;
        float bs = bias ? bias[o] : 0.f;
        #pragma unroll
        for (int j = 0; j < 8; ++j) {
            int nj = n0 + tx * 8 + j;
            if (nj >= Ntot) continue;
            float v = acc[i][j] + bs;
            int bb = nj / HWl, hh = nj % HWl;
            size_t oi = ((size_t)bb * Cout + o) * HWl + hh;
            if (act == 3) {
                float s = scp[oi];
                float sn, cs; sincosf(v, &sn, &cs);
                float re = s * cs, im = s * sn;
                if (addf) { rre[oi] += re; rim[oi] += im; }
                else      { rre[oi]  = re; rim[oi]  = im; }
            } else if (act == 4) {
                outp[oi] = v * scp[oi];
            } else {
                if (act == 1)      v = v >= 0.f ? v : 0.1f * v;
                else if (act == 2) { float rl = fmaxf(v, 0.f); v = ss * rl * rl + sb; }
                outp[oi] = v;
            }
        }
    }
}

// ---------------- rfft2 (ortho) of one [48,48] map -> abs & angle [48,25] ----------------
__global__ __launch_bounds__(256) void k_rfft2(const float* __restrict__ u,
                                               float* __restrict__ A,
                                               float* __restrict__ P)
{
    int bd = blockIdx.x;
    __shared__ float tu[HW_];
    __shared__ float rre[HWF_], rim[HWF_];
    __shared__ float tc[S_], ts[S_];
    int t = threadIdx.x;
    if (t < S_) { double ang = -2.0 * PI_D * (double)t / (double)S_; tc[t] = (float)cos(ang); ts[t] = (float)sin(ang); }
    for (int i = t; i < HW_; i += 256) tu[i] = u[(size_t)bd * HW_ + i];
    __syncthreads();
    for (int i = t; i < HWF_; i += 256) {
        int h = i / FS_, k = i % FS_;
        float ar = 0.f, ai = 0.f;
        int m = 0;
        for (int w = 0; w < S_; ++w) {
            float v = tu[h * S_ + w];
            ar += v * tc[m]; ai += v * ts[m];
            m += k; if (m >= S_) m -= S_;
        }
        rre[i] = ar; rim[i] = ai;
    }
    __syncthreads();
    for (int i = t; i < HWF_; i += 256) {
        int kh = i / FS_, w = i % FS_;
        float ar = 0.f, ai = 0.f;
        int m = 0;
        for (int h = 0; h < S_; ++h) {
            float xr = rre[h * FS_ + w], xi = rim[h * FS_ + w];
            float c = tc[m], s = ts[m];
            ar += xr * c - xi * s;
            ai += xr * s + xi * c;
            m += kh; if (m >= S_) m -= S_;
        }
        ar *= (1.f / 48.f); ai *= (1.f / 48.f);
        A[(size_t)bd * HWF_ + i] = sqrtf(ar * ar + ai * ai);
        P[(size_t)bd * HWF_ + i] = atan2f(ai, ar);
    }
}

// ---------------- in-place abs/angle over forward channel-DFT output slots ----------------
__global__ __launch_bounds__(256) void k_absang(float* __restrict__ CF, long slot)
{
    for (long i = (long)blockIdx.x * 256 + threadIdx.x; i < slot; i += (long)gridDim.x * 256) {
        float re = CF[i], im = CF[slot + i];
        CF[i]        = sqrtf(re * re + im * im);
        CF[slot + i] = atan2f(im, re);
    }
}

// ---------------- build stacked [Re;Im] input for inverse channel GEMM ----------------
// caE in CA2[0][b][k][hw], cpE in CA2[1][..]; RI[b][k][hw]=caE*cos, RI[b][97+k][hw]=caE*sin
__global__ __launch_bounds__(256) void k_buildri(const float* __restrict__ CF,
                                                 float* __restrict__ RI, long slot)
{
    const long row = (long)C2_ * HWF_;           // 116400
    const long brow = (long)CIN2_ * HWF_;        // 232800
    for (long i = (long)blockIdx.x * 256 + threadIdx.x; i < slot; i += (long)gridDim.x * 256) {
        long b = i / row;
        long r = i % row;                        // k*HWF_+hw
        float amp = CF[i], ph = CF[slot + i];
        float sn, cs; sincosf(ph, &sn, &cs);
        RI[b * brow + r]                    = amp * cs;
        RI[b * brow + (long)C2_ * HWF_ + r] = amp * sn;
    }
}

// ---------------- spectrum * routed filter, irfft2 (ortho), + residuals -> out_1 ----------------
__global__ __launch_bounds__(256) void k_final(const float* __restrict__ rre,
                                               const float* __restrict__ rim,
                                               const float* __restrict__ route,
                                               const float* __restrict__ cw,
                                               const float* __restrict__ rin,
                                               const float* __restrict__ tin,
                                               float* __restrict__ out1)
{
    int bd = blockIdx.x;
    int b = bd / D_, d = bd % D_;
    __shared__ float sRe[HWF_], sIm[HWF_];
    __shared__ float cRe[HWF_], cIm[HWF_];
    __shared__ float tc[S_], ts[S_];
    __shared__ float rt[NF_];
    int t = threadIdx.x;
    if (t < S_) { double ang = 2.0 * PI_D * (double)t / (double)S_; tc[t] = (float)cos(ang); ts[t] = (float)sin(ang); }
    if (t < NF_) rt[t] = route[((size_t)b * NF_ + t) * D_ + d];
    __syncthreads();
    for (int i = t; i < HWF_; i += 256) {
        const float* cwp = cw + (size_t)i * NF_ * 2;
        float wr = 0.f, wi = 0.f;
        #pragma unroll
        for (int f = 0; f < NF_; ++f) { wr += rt[f] * cwp[2 * f]; wi += rt[f] * cwp[2 * f + 1]; }
        float xr = rre[(size_t)bd * HWF_ + i], xi = rim[(size_t)bd * HWF_ + i];
        sRe[i] = xr * wr - xi * wi;
        sIm[i] = xr * wi + xi * wr;
    }
    __syncthreads();
    for (int i = t; i < HWF_; i += 256) {
        int hp = i / FS_, w = i % FS_;
        float ar = 0.f, ai = 0.f;
        int m = 0;
        for (int h = 0; h < S_; ++h) {
            float xr = sRe[h * FS_ + w], xi = sIm[h * FS_ + w];
            ar += xr * tc[m] - xi * ts[m];
            ai += xr * ts[m] + xi * tc[m];
            m += hp; if (m >= S_) m -= S_;
        }
        cRe[i] = ar; cIm[i] = ai;
    }
    __syncthreads();
    for (int i = t; i < HW_; i += 256) {
        int hp = i / S_, n = i % S_;
        float acc = cRe[hp * FS_] + ((n & 1) ? -1.f : 1.f) * cRe[hp * FS_ + FS_ - 1];
        float s2 = 0.f;
        int m = n;
        for (int k = 1; k < FS_ - 1; ++k) {
            s2 += cRe[hp * FS_ + k] * tc[m] - cIm[hp * FS_ + k] * ts[m];
            m += n; if (m >= S_) m -= S_;
        }
        float v = (acc + 2.f * s2) * (1.f / 48.f);
        size_t o = (size_t)bd * HW_ + i;
        out1[o] = v + rin[o] + tin[o];
    }
}

// ---------------- BN + depthwise 3x3 + residual -> out ----------------
__global__ __launch_bounds__(256) void k_dw(const float* __restrict__ out1,
                                            const float* __restrict__ g,
                                            const float* __restrict__ bbn,
                                            const float* __restrict__ wdw,
                                            float* __restrict__ outp)
{
    int bd = blockIdx.x;
    int d = bd % D_;
    __shared__ float tile[HW_];
    int t = threadIdx.x;
    for (int i = t; i < HW_; i += 256) tile[i] = out1[(size_t)bd * HW_ + i];
    float sc = g[d] * rsqrtf(1.f + EPS_);
    float bb = bbn[d];
    float w9[9];
    #pragma unroll
    for (int q = 0; q < 9; ++q) w9[q] = wdw[d * 9 + q];
    __syncthreads();
    for (int i = t; i < HW_; i += 256) {
        int y = i / S_, x = i % S_;
        float acc = 0.f;
        #pragma unroll
        for (int ki = 0; ki < 3; ++ki) {
            int yy = y + ki - 1;
            if (yy < 0 || yy >= S_) continue;
            #pragma unroll
            for (int kj = 0; kj < 3; ++kj) {
                int xx = x + kj - 1;
                if (xx < 0 || xx >= S_) continue;
                acc += w9[ki * 3 + kj] * (tile[yy * S_ + xx] * sc + bb);
            }
        }
        outp[(size_t)bd * HW_ + i] = acc + tile[i];
    }
}

// ---------------- launch ----------------
extern "C" void kernel_launch(void* const* d_in, const int* in_sizes, int n_in,
                              void* d_out, int out_size, void* d_ws, size_t ws_size,
                              hipStream_t stream)
{
    (void)in_sizes; (void)n_in; (void)out_size; (void)ws_size;
    const float* r      = (const float*)d_in[0];
    const float* t      = (const float*)d_in[1];
    const float* bn_g   = (const float*)d_in[2];
    const float* bn_b   = (const float*)d_in[3];
    const float* crt_w  = (const float*)d_in[4];
    const float* crt_b  = (const float*)d_in[5];
    const float* star_s = (const float*)d_in[6];
    const float* star_b = (const float*)d_in[7];
    const float* fc1_w  = (const float*)d_in[8];
    const float* fc2_w  = (const float*)d_in[9];
    const float* cw     = (const float*)d_in[10];
    const float* enh_w1 = (const float*)d_in[11];
    const float* enh_b1 = (const float*)d_in[12];
    const float* enh_w2 = (const float*)d_in[13];
    const float* enh_b2 = (const float*)d_in[14];
    const float* ph_w1  = (const float*)d_in[15];
    const float* ph_b1  = (const float*)d_in[16];
    const float* ph_w2  = (const float*)d_in[17];
    const float* ph_b2  = (const float*)d_in[18];
    const float* dwbn_g = (const float*)d_in[19];
    const float* dwbn_b = (const float*)d_in[20];
    const float* dw_w   = (const float*)d_in[21];
    float* out = (float*)d_out;

    const long NDHWF = (long)B_ * D_ * HWF_;     // 3,686,400
    const long SLOTC = (long)B_ * C2_ * HWF_;    // 1,862,400

    float* ws = (float*)d_ws;
    size_t off = 0;
    float* UACT = ws + off; off += (size_t)B_ * D_ * HW_;    // conv act / CH / RI / HT / out_1
    float* A_   = ws + off; off += NDHWF;                    // amplitude a -> sc
    float* P_   = ws + off; off += NDHWF;                    // phase p
    float* RRE  = ws + off; off += NDHWF;                    // rt_s real
    float* RIM  = ws + off; off += NDHWF;                    // rt_s imag
    float* CA2  = ws + off; off += 2 * SLOTC;                // [2 slots]: cf_re->ca->caE, cf_im->cp->cpE
    float* XM   = ws + off; off += B_ * D_;
    float* ROUTE= ws + off; off += B_ * NF_ * D_;
    float* WEFF = ws + off; off += 2 * D_ * D_;
    float* BEFF = ws + off; off += 2 * D_;
    float* TWF  = ws + off; off += 2 * C2_ * D_;             // fwd twiddles (Wfc;Wfs)
    float* TWI  = ws + off; off += (size_t)D_ * CIN2_;       // inv twiddles [192][194]
    float* CH   = UACT;   // enh hidden (2 slots, 3.72M <= 7.08M) — UACT dead after rfft2
    float* RI   = UACT;   // stacked [Re;Im] (3.72M) — CH dead after enh L2
    float* HT   = UACT;   // phase hidden — RI dead after inverse GEMM

    k_prep<<<2 * D_, D_, 0, stream>>>(crt_w, crt_b, bn_g, bn_b, WEFF, BEFF);
    k_twidf<<<C2_, D_, 0, stream>>>(TWF);
    k_twidi<<<D_, 256, 0, stream>>>(TWI);
    k_mean<<<B_ * D_, 256, 0, stream>>>(r, t, bn_g, bn_b, XM);
    k_route<<<B_, 192, 0, stream>>>(XM, fc1_w, fc2_w, star_s, star_b, ROUTE);

    for (int br = 0; br < 2; ++br) {
        const float* u_in = (br == 0) ? r : t;
        const int ia = (br == 0) ? 0 : 2;   // ca-net (cp-net = ia+1, adjacent for z-batch)

        // u = StarReLU(conv1x1(BN(u_in)))
        k_gemm<<<dim3(288, 3, 1), 256, 0, stream>>>(u_in, WEFF + (size_t)br * D_ * D_, BEFF + br * D_,
            UACT, D_, D_, HW_, B_, 2, star_s, star_b, br, 0, 0, 0, 0, nullptr, nullptr, nullptr, 0);
        // spatial rfft2 -> amplitude/phase
        k_rfft2<<<B_ * D_, 256, 0, stream>>>(UACT, A_, P_);
        // channel rfft of amplitude AS GEMM: z=0 -> Re (CA2 slot0), z=1 -> Im (slot1)
        k_gemm<<<dim3(150, 2, 2), 256, 0, stream>>>(A_, TWF, nullptr,
            CA2, D_, C2_, HWF_, B_, 0, nullptr, nullptr, 0,
            0, (long)C2_ * D_, 0, SLOTC, nullptr, nullptr, nullptr, 0);
        // in-place: slot0 = |cf|, slot1 = angle(cf)
        k_absang<<<1024, 256, 0, stream>>>(CA2, SLOTC);
        // enhance nets, z-batched over {ca-net, cp-net}
        k_gemm<<<dim3(150, 2, 2), 256, 0, stream>>>(CA2, enh_w1 + (size_t)ia * C2_ * C2_, enh_b1 + ia * C2_,
            CH, C2_, C2_, HWF_, B_, 1, nullptr, nullptr, 0,
            SLOTC, (long)C2_ * C2_, C2_, SLOTC, nullptr, nullptr, nullptr, 0);
        k_gemm<<<dim3(150, 2, 2), 256, 0, stream>>>(CH, enh_w2 + (size_t)ia * C2_ * C2_, enh_b2 + ia * C2_,
            CA2, C2_, C2_, HWF_, B_, 0, nullptr, nullptr, 0,
            SLOTC, (long)C2_ * C2_, C2_, SLOTC, nullptr, nullptr, nullptr, 0);
        // stacked [caE*cos(cpE); caE*sin(cpE)] -> RI
        k_buildri<<<1024, 256, 0, stream>>>(CA2, RI, SLOTC);
        // channel irfft AS GEMM (Cin=194), epilogue act=4: sc = c * a (scp=A_, in place)
        k_gemm<<<dim3(150, 3, 1), 256, 0, stream>>>(RI, TWI, nullptr,
            A_, CIN2_, D_, HWF_, B_, 4, nullptr, nullptr, 0,
            0, 0, 0, 0, A_, nullptr, nullptr, 0);
        // phase net on p; L2 epilogue fuses combine: rt_s {=,+=} sc*exp(i pE)  (no atomics)
        k_gemm<<<dim3(150, 3, 1), 256, 0, stream>>>(P_, ph_w1 + (size_t)br * D_ * D_, ph_b1 + br * D_,
            HT, D_, D_, HWF_, B_, 1, nullptr, nullptr, 0, 0, 0, 0, 0, nullptr, nullptr, nullptr, 0);
        k_gemm<<<dim3(150, 3, 1), 256, 0, stream>>>(HT, ph_w2 + (size_t)br * D_ * D_, ph_b2 + br * D_,
            P_, D_, D_, HWF_, B_, 3, nullptr, nullptr, 0, 0, 0, 0, 0, A_, RRE, RIM, br);
    }

    // spectrum * routed filters, irfft2, + residuals -> out_1 (in UACT)
    k_final<<<B_ * D_, 256, 0, stream>>>(RRE, RIM, ROUTE, cw, r, t, UACT);
    // BN + depthwise 3x3 + residual -> out
    k_dw<<<B_ * D_, 256, 0, stream>>>(UACT, dwbn_g, dwbn_b, dw_w, out);
}

// Round 15
// 1347.184 us; speedup vs baseline: 1.3363x; 1.0710x over previous
//
#include <hip/hip_runtime.h>
#include <math.h>

// ---------------- problem constants ----------------
constexpr int B_   = 16;
constexpr int D_   = 192;
constexpr int S_   = 48;
constexpr int NF_  = 8;
constexpr int C2_  = 97;   // D/2+1
constexpr int HID_ = 48;
constexpr int FS_  = 25;   // S/2+1
constexpr int HW_  = S_ * S_;    // 2304
constexpr int HWF_ = S_ * FS_;   // 1200
constexpr int CIN2_ = 2 * C2_;   // 194 (stacked Re;Im)
constexpr float EPS_ = 1e-5f;
constexpr double PI_D = 3.14159265358979323846;

// ---------------- prep: fold BN into conv_r/conv_t weights ----------------
__global__ __launch_bounds__(192) void k_prep(const float* __restrict__ crt_w,
                                              const float* __restrict__ crt_b,
                                              const float* __restrict__ bn_g,
                                              const float* __restrict__ bn_b,
                                              float* __restrict__ Weff,
                                              float* __restrict__ beff)
{
    int io = blockIdx.x;            // i*192 + o
    int c  = threadIdx.x;           // 0..191
    int i  = io / D_;
    float s  = bn_g[i * D_ + c] * rsqrtf(1.f + EPS_);
    float bb = bn_b[i * D_ + c];
    float w  = crt_w[(size_t)io * D_ + c];
    Weff[(size_t)io * D_ + c] = w * s;
    __shared__ float red[D_];
    red[c] = w * bb;
    __syncthreads();
    if (c == 0) {
        float acc = 0.f;
        for (int j = 0; j < D_; ++j) acc += red[j];
        int o = io % D_;
        beff[io] = crt_b[i * D_ + o] + acc;
    }
}

// ---------------- forward channel-DFT twiddles: Wfc,Wfs [97][192] ----------------
__global__ __launch_bounds__(192) void k_twidf(float* __restrict__ TWF)
{
    int k = blockIdx.x;     // 0..96
    int d = threadIdx.x;    // 0..191
    double ang = 2.0 * PI_D * (double)(k * d) / (double)D_;
    float nrm = rsqrtf((float)D_);
    TWF[k * D_ + d]              = (float)cos(ang) * nrm;     // Re part of e^{-i ang}
    TWF[C2_ * D_ + k * D_ + d]   = (float)(-sin(ang)) * nrm;  // Im part
}

// ---------------- inverse channel-DFT twiddles: Vinv [192][194] ----------------
__global__ __launch_bounds__(256) void k_twidi(float* __restrict__ TWI)
{
    int d = blockIdx.x;     // 0..191
    int k = threadIdx.x;    // 0..255
    if (k >= CIN2_) return;
    float nrm = rsqrtf((float)D_);
    int j = (k < C2_) ? k : k - C2_;
    double ang = 2.0 * PI_D * (double)(j * d) / (double)D_;
    float v;
    if (k < C2_) {
        if (j == 0)       v = nrm;
        else if (j == 96) v = (d & 1) ? -nrm : nrm;
        else              v = 2.f * (float)cos(ang) * nrm;
    } else {
        if (j == 0 || j == 96) v = 0.f;
        else                   v = -2.f * (float)sin(ang) * nrm;
    }
    TWI[d * CIN2_ + k] = v;
}

// ---------------- mean over HW of bn(r)+bn(t) ----------------
__global__ __launch_bounds__(256) void k_mean(const float* __restrict__ r,
                                              const float* __restrict__ t,
                                              const float* __restrict__ bn_g,
                                              const float* __restrict__ bn_b,
                                              float* __restrict__ xm)
{
    int bd = blockIdx.x;
    int d  = bd % D_;
    float sr = bn_g[d]      * rsqrtf(1.f + EPS_);
    float st = bn_g[D_ + d] * rsqrtf(1.f + EPS_);
    const float* rp = r + (size_t)bd * HW_;
    const float* tp = t + (size_t)bd * HW_;
    float acc = 0.f;
    for (int i = threadIdx.x; i < HW_; i += 256) acc += rp[i] * sr + tp[i] * st;
    __shared__ float red[256];
    red[threadIdx.x] = acc;
    __syncthreads();
    for (int off = 128; off > 0; off >>= 1) {
        if (threadIdx.x < off) red[threadIdx.x] += red[threadIdx.x + off];
        __syncthreads();
    }
    if (threadIdx.x == 0)
        xm[bd] = red[0] * (1.f / HW_) + bn_b[d] + bn_b[D_ + d];
}

// ---------------- routing MLP + softmax over filters ----------------
__global__ __launch_bounds__(192) void k_route(const float* __restrict__ xm,
                                               const float* __restrict__ fc1,
                                               const float* __restrict__ fc2,
                                               const float* __restrict__ star_s,
                                               const float* __restrict__ star_b,
                                               float* __restrict__ route)
{
    int b = blockIdx.x;
    int tid = threadIdx.x;          // 0..191
    __shared__ float x[D_];
    __shared__ float h[HID_];
    x[tid] = xm[b * D_ + tid];
    __syncthreads();
    if (tid < HID_) {
        float a = 0.f;
        const float* wp = fc1 + (size_t)tid * D_;
        for (int c = 0; c < D_; ++c) a += x[c] * wp[c];
        float rl = fmaxf(a, 0.f);
        h[tid] = star_s[2] * rl * rl + star_b[2];
    }
    __syncthreads();
    float lg[NF_];
    for (int f = 0; f < NF_; ++f) {
        const float* wp = fc2 + ((size_t)f * D_ + tid) * HID_;
        float a = 0.f;
        for (int j = 0; j < HID_; ++j) a += h[j] * wp[j];
        lg[f] = a;
    }
    float m = lg[0];
    for (int f = 1; f < NF_; ++f) m = fmaxf(m, lg[f]);
    float ssum = 0.f;
    for (int f = 0; f < NF_; ++f) { lg[f] = expf(lg[f] - m); ssum += lg[f]; }
    float inv = 1.f / ssum;
    for (int f = 0; f < NF_; ++f)
        route[((size_t)b * NF_ + f) * D_ + tid] = lg[f] * inv;
}

// ---------------- channel-GEMM (1x1 conv), 64(O)x128(N) tile, 4x8 acc ----------------
// act: 0 none, 1 leaky(0.1), 2 StarReLU,
//      3 fused combine: rre/rim {=,+=} scp[oi]*exp(i v)  (addf; no atomics)
//      4 scale: out = v * scp[oi]
__global__ __launch_bounds__(256) void k_gemm(const float* __restrict__ in,
                                              const float* __restrict__ W,
                                              const float* __restrict__ bias,
                                              float* __restrict__ outp,
                                              int Cin, int Cout, int HWl, int NB, int act,
                                              const float* __restrict__ ssp,
                                              const float* __restrict__ sbp, int sidx,
                                              long instr, long wstr, long bstr, long ostr,
                                              const float* __restrict__ scp,
                                              float* __restrict__ rre,
                                              float* __restrict__ rim, int addf)
{
    const int z = blockIdx.z;
    in   += (long)z * instr;
    W    += (long)z * wstr;
    if (bias) bias += (long)z * bstr;
    outp += (long)z * ostr;

    const int n0 = blockIdx.x * 128;
    const int o0 = blockIdx.y * 64;
    const int tid = threadIdx.x;
    const int tx = tid & 15;
    const int ty = tid >> 4;
    __shared__ float As[16][72];
    __shared__ float Bs[16][136];
    float acc[4][8] = {};
    const int Ntot = NB * HWl;

    const int akk = tid & 15, aoo0 = tid >> 4;
    const int nn = tid & 127, kb = tid >> 7;
    const int n = n0 + nn;
    const bool nok = n < Ntot;
    int bidx = 0, hw = 0;
    if (nok) { bidx = n / HWl; hw = n % HWl; }
    const float* bp = in + (size_t)bidx * Cin * HWl + hw;

    for (int k0 = 0; k0 < Cin; k0 += 16) {
        #pragma unroll
        for (int j = 0; j < 4; ++j) {
            int oo = aoo0 + 16 * j;
            int o  = o0 + oo;
            int k  = k0 + akk;
            As[akk][oo] = (o < Cout && k < Cin) ? W[(size_t)o * Cin + k] : 0.f;
        }
        #pragma unroll
        for (int j = 0; j < 8; ++j) {
            int kk = kb * 8 + j;
            int k  = k0 + kk;
            Bs[kk][nn] = (nok && k < Cin) ? bp[(size_t)k * HWl] : 0.f;
        }
        __syncthreads();
        #pragma unroll
        for (int kk = 0; kk < 16; ++kk) {
            float4 av = *reinterpret_cast<const float4*>(&As[kk][ty * 4]);
            float4 b0 = *reinterpret_cast<const float4*>(&Bs[kk][tx * 8]);
            float4 b1 = *reinterpret_cast<const float4*>(&Bs[kk][tx * 8 + 4]);
            float a4[4] = {av.x, av.y, av.z, av.w};
            float b8[8] = {b0.x, b0.y, b0.z, b0.w, b1.x, b1.y, b1.z, b1.w};
            #pragma unroll
            for (int i = 0; i < 4; ++i)
                #pragma unroll
                for (int j = 0; j < 8; ++j)
                    acc[i][j] += a4[i] * b8[j];
        }
        __syncthreads();
    }

    float ss = 0.f, sb = 0.f;
    if (act == 2) { ss = ssp[sidx]; sb = sbp[sidx]; }
    #pragma unroll
    for (int i = 0; i < 4; ++i) {
        int o = o0 + ty * 4 + i;
        if (o >= Cout) continue;
        float bs = bias ? bias[o] : 0.f;
        #pragma unroll
        for (int j = 0; j < 8; ++j) {
            int nj = n0 + tx * 8 + j;
            if (nj >= Ntot) continue;
            float v = acc[i][j] + bs;
            int bb = nj / HWl, hh = nj % HWl;
            size_t oi = ((size_t)bb * Cout + o) * HWl + hh;
            if (act == 3) {
                float s = scp[oi];
                float sn, cs; sincosf(v, &sn, &cs);
                float re = s * cs, im = s * sn;
                if (addf) { rre[oi] += re; rim[oi] += im; }
                else      { rre[oi]  = re; rim[oi]  = im; }
            } else if (act == 4) {
                outp[oi] = v * scp[oi];
            } else {
                if (act == 1)      v = v >= 0.f ? v : 0.1f * v;
                else if (act == 2) { float rl = fmaxf(v, 0.f); v = ss * rl * rl + sb; }
                outp[oi] = v;
            }
        }
    }
}

// ---------------- rfft2 (ortho): rows naive, 48-pt column DFT via radix-4 ----------------
__global__ __launch_bounds__(256) void k_rfft2(const float* __restrict__ u,
                                               float* __restrict__ A,
                                               float* __restrict__ P)
{
    int bd = blockIdx.x;
    __shared__ float tu[HW_];
    __shared__ float rre[HWF_], rim[HWF_];
    __shared__ float yre[HWF_], yim[HWF_];
    __shared__ float tc[S_], ts[S_];
    int t = threadIdx.x;
    if (t < S_) { double ang = -2.0 * PI_D * (double)t / (double)S_; tc[t] = (float)cos(ang); ts[t] = (float)sin(ang); }
    for (int i = t; i < HW_; i += 256) tu[i] = u[(size_t)bd * HW_ + i];
    __syncthreads();
    // rows: real 48 -> complex 25
    for (int i = t; i < HWF_; i += 256) {
        int h = i / FS_, k = i % FS_;
        float ar = 0.f, ai = 0.f;
        int m = 0;
        for (int w = 0; w < S_; ++w) {
            float v = tu[h * S_ + w];
            ar += v * tc[m]; ai += v * ts[m];
            m += k; if (m >= S_) m -= S_;
        }
        rre[i] = ar; rim[i] = ai;
    }
    __syncthreads();
    // col DFT stage A: Y_r[j][w] = sum_m x[4m+r][w] e^{-2pi i mj/12}
    for (int i = t; i < HWF_; i += 256) {
        int r = i / 300, j = (i / FS_) % 12, w = i % FS_;
        float ar = 0.f, ai = 0.f;
        int mj = 0;
        #pragma unroll
        for (int m = 0; m < 12; ++m) {
            int hh = 4 * m + r;
            float xr = rre[hh * FS_ + w], xi = rim[hh * FS_ + w];
            float c = tc[4 * mj], s = ts[4 * mj];
            ar += xr * c - xi * s;
            ai += xr * s + xi * c;
            mj += j; if (mj >= 12) mj -= 12;
        }
        yre[i] = ar; yim[i] = ai;
    }
    __syncthreads();
    // col DFT stage B: X[kh][w] = sum_r e^{-2pi i r kh/48} Y_r[kh%12][w]; |.| and angle (1/48)
    for (int i = t; i < HWF_; i += 256) {
        int kh = i / FS_, w = i % FS_, j = kh % 12;
        float ar = 0.f, ai = 0.f;
        int rk = 0;
        #pragma unroll
        for (int r = 0; r < 4; ++r) {
            float xr = yre[(r * 12 + j) * FS_ + w], xi = yim[(r * 12 + j) * FS_ + w];
            float c = tc[rk], s = ts[rk];
            ar += xr * c - xi * s;
            ai += xr * s + xi * c;
            rk += kh; if (rk >= S_) rk -= S_;
        }
        ar *= (1.f / 48.f); ai *= (1.f / 48.f);
        A[(size_t)bd * HWF_ + i] = sqrtf(ar * ar + ai * ai);
        P[(size_t)bd * HWF_ + i] = atan2f(ai, ar);
    }
}

// ---------------- in-place abs/angle over forward channel-DFT output slots ----------------
__global__ __launch_bounds__(256) void k_absang(float* __restrict__ CF, long slot)
{
    for (long i = (long)blockIdx.x * 256 + threadIdx.x; i < slot; i += (long)gridDim.x * 256) {
        float re = CF[i], im = CF[slot + i];
        CF[i]        = sqrtf(re * re + im * im);
        CF[slot + i] = atan2f(im, re);
    }
}

// ---------------- build stacked [Re;Im] input for inverse channel GEMM ----------------
__global__ __launch_bounds__(256) void k_buildri(const float* __restrict__ CF,
                                                 float* __restrict__ RI, long slot)
{
    const long row = (long)C2_ * HWF_;           // 116400
    const long brow = (long)CIN2_ * HWF_;        // 232800
    for (long i = (long)blockIdx.x * 256 + threadIdx.x; i < slot; i += (long)gridDim.x * 256) {
        long b = i / row;
        long r = i % row;
        float amp = CF[i], ph = CF[slot + i];
        float sn, cs; sincosf(ph, &sn, &cs);
        RI[b * brow + r]                    = amp * cs;
        RI[b * brow + (long)C2_ * HWF_ + r] = amp * sn;
    }
}

// ---------------- spectrum * routed filter, irfft2 (radix-4 col), + residuals -> out_1 ----------------
__global__ __launch_bounds__(256) void k_final(const float* __restrict__ rre,
                                               const float* __restrict__ rim,
                                               const float* __restrict__ route,
                                               const float* __restrict__ cw,
                                               const float* __restrict__ rin,
                                               const float* __restrict__ tin,
                                               float* __restrict__ out1)
{
    int bd = blockIdx.x;
    int b = bd / D_, d = bd % D_;
    __shared__ float sRe[HWF_], sIm[HWF_];
    __shared__ float yre[HWF_], yim[HWF_];
    __shared__ float cRe[HWF_], cIm[HWF_];
    __shared__ float tc[S_], ts[S_];
    __shared__ float rt[NF_];
    int t = threadIdx.x;
    if (t < S_) { double ang = 2.0 * PI_D * (double)t / (double)S_; tc[t] = (float)cos(ang); ts[t] = (float)sin(ang); }
    if (t < NF_) rt[t] = route[((size_t)b * NF_ + t) * D_ + d];
    __syncthreads();
    // build spectrum: rt_s * (route . cw)
    for (int i = t; i < HWF_; i += 256) {
        const float* cwp = cw + (size_t)i * NF_ * 2;
        float wr = 0.f, wi = 0.f;
        #pragma unroll
        for (int f = 0; f < NF_; ++f) { wr += rt[f] * cwp[2 * f]; wi += rt[f] * cwp[2 * f + 1]; }
        float xr = rre[(size_t)bd * HWF_ + i], xi = rim[(size_t)bd * HWF_ + i];
        sRe[i] = xr * wr - xi * wi;
        sIm[i] = xr * wi + xi * wr;
    }
    __syncthreads();
    // inverse col DFT stage A: Y_r[j][w] = sum_m s[4m+r][w] e^{+2pi i mj/12}
    for (int i = t; i < HWF_; i += 256) {
        int r = i / 300, j = (i / FS_) % 12, w = i % FS_;
        float ar = 0.f, ai = 0.f;
        int mj = 0;
        #pragma unroll
        for (int m = 0; m < 12; ++m) {
            int hh = 4 * m + r;
            float xr = sRe[hh * FS_ + w], xi = sIm[hh * FS_ + w];
            float c = tc[4 * mj], s = ts[4 * mj];
            ar += xr * c - xi * s;
            ai += xr * s + xi * c;
            mj += j; if (mj >= 12) mj -= 12;
        }
        yre[i] = ar; yim[i] = ai;
    }
    __syncthreads();
    // inverse col DFT stage B: X[hp][w] = sum_r e^{+2pi i r hp/48} Y_r[hp%12][w]
    for (int i = t; i < HWF_; i += 256) {
        int hp = i / FS_, w = i % FS_, j = hp % 12;
        float ar = 0.f, ai = 0.f;
        int rk = 0;
        #pragma unroll
        for (int r = 0; r < 4; ++r) {
            float xr = yre[(r * 12 + j) * FS_ + w], xi = yim[(r * 12 + j) * FS_ + w];
            float c = tc[rk], s = ts[rk];
            ar += xr * c - xi * s;
            ai += xr * s + xi * c;
            rk += hp; if (rk >= S_) rk -= S_;
        }
        cRe[i] = ar; cIm[i] = ai;
    }
    __syncthreads();
    // row irfft 25 -> 48, total ortho scale 1/48; add residuals
    for (int i = t; i < HW_; i += 256) {
        int hp = i / S_, n = i % S_;
        float acc = cRe[hp * FS_] + ((n & 1) ? -1.f : 1.f) * cRe[hp * FS_ + FS_ - 1];
        float s2 = 0.f;
        int m = n;
        for (int k = 1; k < FS_ - 1; ++k) {
            s2 += cRe[hp * FS_ + k] * tc[m] - cIm[hp * FS_ + k] * ts[m];
            m += n; if (m >= S_) m -= S_;
        }
        float v = (acc + 2.f * s2) * (1.f / 48.f);
        size_t o = (size_t)bd * HW_ + i;
        out1[o] = v + rin[o] + tin[o];
    }
}

// ---------------- BN + depthwise 3x3 + residual -> out ----------------
__global__ __launch_bounds__(256) void k_dw(const float* __restrict__ out1,
                                            const float* __restrict__ g,
                                            const float* __restrict__ bbn,
                                            const float* __restrict__ wdw,
                                            float* __restrict__ outp)
{
    int bd = blockIdx.x;
    int d = bd % D_;
    __shared__ float tile[HW_];
    int t = threadIdx.x;
    for (int i = t; i < HW_; i += 256) tile[i] = out1[(size_t)bd * HW_ + i];
    float sc = g[d] * rsqrtf(1.f + EPS_);
    float bb = bbn[d];
    float w9[9];
    #pragma unroll
    for (int q = 0; q < 9; ++q) w9[q] = wdw[d * 9 + q];
    __syncthreads();
    for (int i = t; i < HW_; i += 256) {
        int y = i / S_, x = i % S_;
        float acc = 0.f;
        #pragma unroll
        for (int ki = 0; ki < 3; ++ki) {
            int yy = y + ki - 1;
            if (yy < 0 || yy >= S_) continue;
            #pragma unroll
            for (int kj = 0; kj < 3; ++kj) {
                int xx = x + kj - 1;
                if (xx < 0 || xx >= S_) continue;
                acc += w9[ki * 3 + kj] * (tile[yy * S_ + xx] * sc + bb);
            }
        }
        outp[(size_t)bd * HW_ + i] = acc + tile[i];
    }
}

// ---------------- launch ----------------
extern "C" void kernel_launch(void* const* d_in, const int* in_sizes, int n_in,
                              void* d_out, int out_size, void* d_ws, size_t ws_size,
                              hipStream_t stream)
{
    (void)in_sizes; (void)n_in; (void)out_size; (void)ws_size;
    const float* r      = (const float*)d_in[0];
    const float* t      = (const float*)d_in[1];
    const float* bn_g   = (const float*)d_in[2];
    const float* bn_b   = (const float*)d_in[3];
    const float* crt_w  = (const float*)d_in[4];
    const float* crt_b  = (const float*)d_in[5];
    const float* star_s = (const float*)d_in[6];
    const float* star_b = (const float*)d_in[7];
    const float* fc1_w  = (const float*)d_in[8];
    const float* fc2_w  = (const float*)d_in[9];
    const float* cw     = (const float*)d_in[10];
    const float* enh_w1 = (const float*)d_in[11];
    const float* enh_b1 = (const float*)d_in[12];
    const float* enh_w2 = (const float*)d_in[13];
    const float* enh_b2 = (const float*)d_in[14];
    const float* ph_w1  = (const float*)d_in[15];
    const float* ph_b1  = (const float*)d_in[16];
    const float* ph_w2  = (const float*)d_in[17];
    const float* ph_b2  = (const float*)d_in[18];
    const float* dwbn_g = (const float*)d_in[19];
    const float* dwbn_b = (const float*)d_in[20];
    const float* dw_w   = (const float*)d_in[21];
    float* out = (float*)d_out;

    const long NDHWF = (long)B_ * D_ * HWF_;     // 3,686,400
    const long SLOTC = (long)B_ * C2_ * HWF_;    // 1,862,400

    float* ws = (float*)d_ws;
    size_t off = 0;
    float* UACT = ws + off; off += (size_t)B_ * D_ * HW_;    // conv act / CH / RI / HT / out_1
    float* A_   = ws + off; off += NDHWF;                    // amplitude a -> sc
    float* P_   = ws + off; off += NDHWF;                    // phase p
    float* RRE  = ws + off; off += NDHWF;                    // rt_s real
    float* RIM  = ws + off; off += NDHWF;                    // rt_s imag
    float* CA2  = ws + off; off += 2 * SLOTC;                // [2 slots]: cf_re->ca->caE, cf_im->cp->cpE
    float* XM   = ws + off; off += B_ * D_;
    float* ROUTE= ws + off; off += B_ * NF_ * D_;
    float* WEFF = ws + off; off += 2 * D_ * D_;
    float* BEFF = ws + off; off += 2 * D_;
    float* TWF  = ws + off; off += 2 * C2_ * D_;             // fwd twiddles (Wfc;Wfs)
    float* TWI  = ws + off; off += (size_t)D_ * CIN2_;       // inv twiddles [192][194]
    float* CH   = UACT;   // enh hidden (2 slots) — UACT dead after rfft2
    float* RI   = UACT;   // stacked [Re;Im] — CH dead after enh L2
    float* HT   = UACT;   // phase hidden — RI dead after inverse GEMM

    k_prep<<<2 * D_, D_, 0, stream>>>(crt_w, crt_b, bn_g, bn_b, WEFF, BEFF);
    k_twidf<<<C2_, D_, 0, stream>>>(TWF);
    k_twidi<<<D_, 256, 0, stream>>>(TWI);
    k_mean<<<B_ * D_, 256, 0, stream>>>(r, t, bn_g, bn_b, XM);
    k_route<<<B_, 192, 0, stream>>>(XM, fc1_w, fc2_w, star_s, star_b, ROUTE);

    for (int br = 0; br < 2; ++br) {
        const float* u_in = (br == 0) ? r : t;
        const int ia = (br == 0) ? 0 : 2;   // ca-net (cp-net = ia+1, adjacent for z-batch)

        // u = StarReLU(conv1x1(BN(u_in)))
        k_gemm<<<dim3(288, 3, 1), 256, 0, stream>>>(u_in, WEFF + (size_t)br * D_ * D_, BEFF + br * D_,
            UACT, D_, D_, HW_, B_, 2, star_s, star_b, br, 0, 0, 0, 0, nullptr, nullptr, nullptr, 0);
        // spatial rfft2 (radix-4 columns) -> amplitude/phase
        k_rfft2<<<B_ * D_, 256, 0, stream>>>(UACT, A_, P_);
        // channel rfft of amplitude AS GEMM: z=0 -> Re (CA2 slot0), z=1 -> Im (slot1)
        k_gemm<<<dim3(150, 2, 2), 256, 0, stream>>>(A_, TWF, nullptr,
            CA2, D_, C2_, HWF_, B_, 0, nullptr, nullptr, 0,
            0, (long)C2_ * D_, 0, SLOTC, nullptr, nullptr, nullptr, 0);
        // in-place: slot0 = |cf|, slot1 = angle(cf)
        k_absang<<<1024, 256, 0, stream>>>(CA2, SLOTC);
        // enhance nets, z-batched over {ca-net, cp-net}
        k_gemm<<<dim3(150, 2, 2), 256, 0, stream>>>(CA2, enh_w1 + (size_t)ia * C2_ * C2_, enh_b1 + ia * C2_,
            CH, C2_, C2_, HWF_, B_, 1, nullptr, nullptr, 0,
            SLOTC, (long)C2_ * C2_, C2_, SLOTC, nullptr, nullptr, nullptr, 0);
        k_gemm<<<dim3(150, 2, 2), 256, 0, stream>>>(CH, enh_w2 + (size_t)ia * C2_ * C2_, enh_b2 + ia * C2_,
            CA2, C2_, C2_, HWF_, B_, 0, nullptr, nullptr, 0,
            SLOTC, (long)C2_ * C2_, C2_, SLOTC, nullptr, nullptr, nullptr, 0);
        // stacked [caE*cos(cpE); caE*sin(cpE)] -> RI
        k_buildri<<<1024, 256, 0, stream>>>(CA2, RI, SLOTC);
        // channel irfft AS GEMM (Cin=194), epilogue act=4: sc = c * a (scp=A_, in place)
        k_gemm<<<dim3(150, 3, 1), 256, 0, stream>>>(RI, TWI, nullptr,
            A_, CIN2_, D_, HWF_, B_, 4, nullptr, nullptr, 0,
            0, 0, 0, 0, A_, nullptr, nullptr, 0);
        // phase net on p; L2 epilogue fuses combine: rt_s {=,+=} sc*exp(i pE)  (no atomics)
        k_gemm<<<dim3(150, 3, 1), 256, 0, stream>>>(P_, ph_w1 + (size_t)br * D_ * D_, ph_b1 + br * D_,
            HT, D_, D_, HWF_, B_, 1, nullptr, nullptr, 0, 0, 0, 0, 0, nullptr, nullptr, nullptr, 0);
        k_gemm<<<dim3(150, 3, 1), 256, 0, stream>>>(HT, ph_w2 + (size_t)br * D_ * D_, ph_b2 + br * D_,
            P_, D_, D_, HWF_, B_, 3, nullptr, nullptr, 0, 0, 0, 0, 0, A_, RRE, RIM, br);
    }

    // spectrum * routed filters, irfft2 (radix-4 col), + residuals -> out_1 (in UACT)
    k_final<<<B_ * D_, 256, 0, stream>>>(RRE, RIM, ROUTE, cw, r, t, UACT);
    // BN + depthwise 3x3 + residual -> out
    k_dw<<<B_ * D_, 256, 0, stream>>>(UACT, dwbn_g, dwbn_b, dw_w, out);
}